// Round 1
// baseline (3798.974 us; speedup 1.0000x reference)
//
#include <hip/hip_runtime.h>
#include <math.h>

// Problem constants
#define B_  2
#define T_  2048
#define D_  2048
#define H_  16
#define HD_ 128
// qkv row stride (3*D)
#define QKV_LD 6144

// ---------------------------------------------------------------------------
// fp32 GEMM: C[M,N] = A[M,K] @ B[K,N], all row-major.
// BM=BN=128, BK=16, 256 threads, 8x8 micro-tile per thread.
// Assumes M%128==0, N%128==0, K%16==0 (true for all uses here).
// ---------------------------------------------------------------------------
__global__ __launch_bounds__(256)
void gemm_f32(const float* __restrict__ A, const float* __restrict__ Bm,
              float* __restrict__ C, int M, int N, int K) {
    __shared__ float As[16][128];   // transposed: As[k][m]
    __shared__ float Bs[16][128];   // Bs[k][n]

    const int tid = threadIdx.x;
    const int tm = tid >> 4;        // 0..15
    const int tn = tid & 15;        // 0..15
    const int m0 = blockIdx.y * 128;
    const int n0 = blockIdx.x * 128;

    float acc[8][8];
    #pragma unroll
    for (int i = 0; i < 8; ++i)
        #pragma unroll
        for (int j = 0; j < 8; ++j) acc[i][j] = 0.f;

    for (int k0 = 0; k0 < K; k0 += 16) {
        // Load A tile 128x16 (512 float4, 2 per thread), store transposed
        #pragma unroll
        for (int i = 0; i < 2; ++i) {
            int f   = tid + i * 256;
            int row = f >> 2;
            int kq  = f & 3;
            float4 a = *(const float4*)(A + (size_t)(m0 + row) * K + k0 + kq * 4);
            As[kq * 4 + 0][row] = a.x;
            As[kq * 4 + 1][row] = a.y;
            As[kq * 4 + 2][row] = a.z;
            As[kq * 4 + 3][row] = a.w;
        }
        // Load B tile 16x128 (512 float4, 2 per thread)
        #pragma unroll
        for (int i = 0; i < 2; ++i) {
            int f   = tid + i * 256;
            int row = f >> 5;
            int c4  = f & 31;
            *(float4*)(&Bs[row][c4 * 4]) =
                *(const float4*)(Bm + (size_t)(k0 + row) * N + n0 + c4 * 4);
        }
        __syncthreads();

        #pragma unroll
        for (int kk = 0; kk < 16; ++kk) {
            float4 a0 = *(const float4*)(&As[kk][tm * 4]);
            float4 a1 = *(const float4*)(&As[kk][tm * 4 + 64]);
            float4 b0 = *(const float4*)(&Bs[kk][tn * 4]);
            float4 b1 = *(const float4*)(&Bs[kk][tn * 4 + 64]);
            float av[8] = {a0.x, a0.y, a0.z, a0.w, a1.x, a1.y, a1.z, a1.w};
            float bv[8] = {b0.x, b0.y, b0.z, b0.w, b1.x, b1.y, b1.z, b1.w};
            #pragma unroll
            for (int i = 0; i < 8; ++i)
                #pragma unroll
                for (int j = 0; j < 8; ++j)
                    acc[i][j] = fmaf(av[i], bv[j], acc[i][j]);
        }
        __syncthreads();
    }

    // Write C: 8 rows x 2 float4
    #pragma unroll
    for (int i = 0; i < 8; ++i) {
        int r = m0 + ((i < 4) ? (tm * 4 + i) : (64 + tm * 4 + (i - 4)));
        float4 c0 = make_float4(acc[i][0], acc[i][1], acc[i][2], acc[i][3]);
        float4 c1 = make_float4(acc[i][4], acc[i][5], acc[i][6], acc[i][7]);
        *(float4*)(C + (size_t)r * N + n0 + tn * 4)      = c0;
        *(float4*)(C + (size_t)r * N + n0 + tn * 4 + 64) = c1;
    }
}

// ---------------------------------------------------------------------------
// RoPE in-place on q,k halves of qkv [B*T, 3D].
// One thread per (row, q/k, pair). Interleaved pairs (2i, 2i+1).
// freqs_cis: [T, HD/2, 2] (cos, sin)
// ---------------------------------------------------------------------------
__global__ __launch_bounds__(256)
void rope_kernel(float* __restrict__ qkv, const float* __restrict__ fc) {
    int gid = blockIdx.x * 256 + threadIdx.x;     // B_*T_*2048 total
    int row = gid >> 11;            // b*T + t
    int rem = gid & 2047;
    int sel = rem >> 10;            // 0 = q, 1 = k
    int pi  = rem & 1023;           // h*64 + i
    int h   = pi >> 6;
    int i   = pi & 63;
    int t   = row & (T_ - 1);

    float2 cs = *(const float2*)(fc + ((size_t)t * 64 + i) * 2);
    float* p  = qkv + (size_t)row * QKV_LD + sel * D_ + h * HD_ + i * 2;
    float2 v  = *(float2*)p;
    float o0 = v.x * cs.x - v.y * cs.y;
    float o1 = v.y * cs.x + v.x * cs.y;
    *(float2*)p = make_float2(o0, o1);
}

// ---------------------------------------------------------------------------
// Flash attention (causal), fp32, online softmax.
// Grid: (T/32, B*H). Block: 256 threads (16x16 grid), QT=KT=32 tiles.
// Thread (tm,tn): scores for rows {2tm,2tm+1} x cols {2tn,2tn+1};
// output acc for rows {2tm,2tm+1} x dims {tn*4..+3, 64+tn*4..+3}.
// LDS rows padded to 132 floats (33 float4) to spread banks.
// ---------------------------------------------------------------------------
#define LSTR 132   // padded row stride in floats (33 float4)

__global__ __launch_bounds__(256)
void attn_kernel(const float* __restrict__ qkv, float* __restrict__ out) {
    __shared__ float Qs[32 * LSTR];
    __shared__ float Ks[32 * LSTR];
    __shared__ float Vs[32 * LSTR];
    __shared__ float Ps[32 * 33];

    const int tid = threadIdx.x;
    const int tm  = tid >> 4;       // 0..15
    const int tn  = tid & 15;       // 0..15
    const int bh  = blockIdx.y;     // 0..31
    const int b   = bh >> 4;
    const int h   = bh & 15;
    const int qt  = blockIdx.x;     // q tile index
    const int qt0 = qt * 32;
    const float scale = 0.08838834764831845f;  // 1/sqrt(128)

    // Load Q tile (32 x 128)
    {
        const float* qbase = qkv + ((size_t)(b * T_ + qt0)) * QKV_LD + h * HD_;
        #pragma unroll
        for (int i = 0; i < 4; ++i) {
            int f  = tid + i * 256;     // 1024 float4
            int r  = f >> 5;
            int d4 = f & 31;
            *(float4*)(&Qs[r * LSTR + d4 * 4]) =
                *(const float4*)(qbase + (size_t)r * QKV_LD + d4 * 4);
        }
    }

    const int r0 = tm * 2, r1 = tm * 2 + 1;
    float m0r = -INFINITY, m1r = -INFINITY;
    float l0 = 0.f, l1 = 0.f;
    float o[2][8];
    #pragma unroll
    for (int j = 0; j < 8; ++j) { o[0][j] = 0.f; o[1][j] = 0.f; }

    for (int kt = 0; kt <= qt; ++kt) {
        // Load K,V tiles (32 x 128 each)
        const float* kbase = qkv + ((size_t)(b * T_ + kt * 32)) * QKV_LD + D_ + h * HD_;
        const float* vbase = kbase + D_;
        #pragma unroll
        for (int i = 0; i < 4; ++i) {
            int f  = tid + i * 256;
            int r  = f >> 5;
            int d4 = f & 31;
            *(float4*)(&Ks[r * LSTR + d4 * 4]) =
                *(const float4*)(kbase + (size_t)r * QKV_LD + d4 * 4);
            *(float4*)(&Vs[r * LSTR + d4 * 4]) =
                *(const float4*)(vbase + (size_t)r * QKV_LD + d4 * 4);
        }
        __syncthreads();

        // Scores 2x2
        float s00 = 0.f, s01 = 0.f, s10 = 0.f, s11 = 0.f;
        const int c0 = 2 * tn, c1 = 2 * tn + 1;
        #pragma unroll
        for (int d4 = 0; d4 < 32; ++d4) {
            float4 q0 = *(const float4*)(&Qs[r0 * LSTR + d4 * 4]);
            float4 q1 = *(const float4*)(&Qs[r1 * LSTR + d4 * 4]);
            float4 k0 = *(const float4*)(&Ks[c0 * LSTR + d4 * 4]);
            float4 k1 = *(const float4*)(&Ks[c1 * LSTR + d4 * 4]);
            s00 = fmaf(q0.x, k0.x, s00); s00 = fmaf(q0.y, k0.y, s00);
            s00 = fmaf(q0.z, k0.z, s00); s00 = fmaf(q0.w, k0.w, s00);
            s01 = fmaf(q0.x, k1.x, s01); s01 = fmaf(q0.y, k1.y, s01);
            s01 = fmaf(q0.z, k1.z, s01); s01 = fmaf(q0.w, k1.w, s01);
            s10 = fmaf(q1.x, k0.x, s10); s10 = fmaf(q1.y, k0.y, s10);
            s10 = fmaf(q1.z, k0.z, s10); s10 = fmaf(q1.w, k0.w, s10);
            s11 = fmaf(q1.x, k1.x, s11); s11 = fmaf(q1.y, k1.y, s11);
            s11 = fmaf(q1.z, k1.z, s11); s11 = fmaf(q1.w, k1.w, s11);
        }
        s00 *= scale; s01 *= scale; s10 *= scale; s11 *= scale;

        // Causal mask on diagonal tile (local col > local row)
        if (kt == qt) {
            if (c0 > r0) s00 = -INFINITY;
            if (c1 > r0) s01 = -INFINITY;
            if (c0 > r1) s10 = -INFINITY;
            if (c1 > r1) s11 = -INFINITY;
        }

        // Row max across the 16 tn lanes
        float mt0 = fmaxf(s00, s01);
        float mt1 = fmaxf(s10, s11);
        #pragma unroll
        for (int off = 1; off < 16; off <<= 1) {
            mt0 = fmaxf(mt0, __shfl_xor(mt0, off));
            mt1 = fmaxf(mt1, __shfl_xor(mt1, off));
        }
        float mn0 = fmaxf(m0r, mt0);
        float mn1 = fmaxf(m1r, mt1);
        float cr0 = __expf(m0r - mn0);
        float cr1 = __expf(m1r - mn1);
        float p00 = __expf(s00 - mn0), p01 = __expf(s01 - mn0);
        float p10 = __expf(s10 - mn1), p11 = __expf(s11 - mn1);
        float rs0 = p00 + p01;
        float rs1 = p10 + p11;
        #pragma unroll
        for (int off = 1; off < 16; off <<= 1) {
            rs0 += __shfl_xor(rs0, off);
            rs1 += __shfl_xor(rs1, off);
        }
        l0 = l0 * cr0 + rs0;
        l1 = l1 * cr1 + rs1;
        m0r = mn0; m1r = mn1;
        #pragma unroll
        for (int j = 0; j < 8; ++j) { o[0][j] *= cr0; o[1][j] *= cr1; }

        Ps[r0 * 33 + c0] = p00; Ps[r0 * 33 + c1] = p01;
        Ps[r1 * 33 + c0] = p10; Ps[r1 * 33 + c1] = p11;
        __syncthreads();

        // PV: o[r][d] += P[r][k] * V[k][d]
        #pragma unroll
        for (int k = 0; k < 32; ++k) {
            float p0 = Ps[r0 * 33 + k];
            float p1 = Ps[r1 * 33 + k];
            float4 v0 = *(const float4*)(&Vs[k * LSTR + tn * 4]);
            float4 v1 = *(const float4*)(&Vs[k * LSTR + 64 + tn * 4]);
            o[0][0] = fmaf(p0, v0.x, o[0][0]);
            o[0][1] = fmaf(p0, v0.y, o[0][1]);
            o[0][2] = fmaf(p0, v0.z, o[0][2]);
            o[0][3] = fmaf(p0, v0.w, o[0][3]);
            o[0][4] = fmaf(p0, v1.x, o[0][4]);
            o[0][5] = fmaf(p0, v1.y, o[0][5]);
            o[0][6] = fmaf(p0, v1.z, o[0][6]);
            o[0][7] = fmaf(p0, v1.w, o[0][7]);
            o[1][0] = fmaf(p1, v0.x, o[1][0]);
            o[1][1] = fmaf(p1, v0.y, o[1][1]);
            o[1][2] = fmaf(p1, v0.z, o[1][2]);
            o[1][3] = fmaf(p1, v0.w, o[1][3]);
            o[1][4] = fmaf(p1, v1.x, o[1][4]);
            o[1][5] = fmaf(p1, v1.y, o[1][5]);
            o[1][6] = fmaf(p1, v1.z, o[1][6]);
            o[1][7] = fmaf(p1, v1.w, o[1][7]);
        }
        __syncthreads();   // protect Ks/Vs/Ps before next tile
    }

    // Epilogue: write O / l to attn buffer [B*T, D] at (b,t,h,hd)
    float inv0 = 1.f / l0;
    float inv1 = 1.f / l1;
    float* obase = out + ((size_t)(b * T_ + qt0)) * D_ + h * HD_;
    float4 w00 = make_float4(o[0][0] * inv0, o[0][1] * inv0, o[0][2] * inv0, o[0][3] * inv0);
    float4 w01 = make_float4(o[0][4] * inv0, o[0][5] * inv0, o[0][6] * inv0, o[0][7] * inv0);
    float4 w10 = make_float4(o[1][0] * inv1, o[1][1] * inv1, o[1][2] * inv1, o[1][3] * inv1);
    float4 w11 = make_float4(o[1][4] * inv1, o[1][5] * inv1, o[1][6] * inv1, o[1][7] * inv1);
    *(float4*)(obase + (size_t)r0 * D_ + tn * 4)      = w00;
    *(float4*)(obase + (size_t)r0 * D_ + 64 + tn * 4) = w01;
    *(float4*)(obase + (size_t)r1 * D_ + tn * 4)      = w10;
    *(float4*)(obase + (size_t)r1 * D_ + 64 + tn * 4) = w11;
}

// ---------------------------------------------------------------------------
// Launch
// ---------------------------------------------------------------------------
extern "C" void kernel_launch(void* const* d_in, const int* in_sizes, int n_in,
                              void* d_out, int out_size, void* d_ws, size_t ws_size,
                              hipStream_t stream) {
    const float* x    = (const float*)d_in[0];  // [B,T,D]
    const float* Wqkv = (const float*)d_in[1];  // [D, 3D]
    const float* Wout = (const float*)d_in[2];  // [D, D]
    const float* fc   = (const float*)d_in[3];  // [T, HD/2, 2]
    float* out = (float*)d_out;                 // [B,T,D]

    float* qkv  = (float*)d_ws;                                   // [B*T, 3D] = 96 MB
    float* attn = (float*)((char*)d_ws + (size_t)4096 * 6144 * 4); // [B*T, D] = 32 MB

    dim3 blk(256);

    // 1) qkv = x @ Wqkv    (M=4096, N=6144, K=2048)
    gemm_f32<<<dim3(6144 / 128, 4096 / 128), blk, 0, stream>>>(x, Wqkv, qkv, 4096, 6144, 2048);

    // 2) RoPE in-place on q,k
    rope_kernel<<<dim3((B_ * T_ * 2048) / 256), blk, 0, stream>>>(qkv, fc);

    // 3) causal flash attention -> attn [B*T, D] (layout b,t,h,hd)
    attn_kernel<<<dim3(T_ / 32, B_ * H_), blk, 0, stream>>>(qkv, attn);

    // 4) out = attn @ Wout (M=4096, N=2048, K=2048)
    gemm_f32<<<dim3(2048 / 128, 4096 / 128), blk, 0, stream>>>(attn, Wout, out, 4096, 2048, 2048);
}

// Round 3
// 470.551 us; speedup vs baseline: 8.0735x; 8.0735x over previous
//
#include <hip/hip_runtime.h>
#include <math.h>

// Problem constants
#define B_   2
#define T_   2048
#define D_   2048
#define H_   16
#define HD_  128
#define QKV_LD 6144
#define SCALE 0.08838834764831845f  // 1/sqrt(128)

typedef __attribute__((ext_vector_type(4))) float f32x4;
typedef __attribute__((ext_vector_type(8))) short bf16x8;

static __device__ __forceinline__ unsigned short f2bf(float f) {
    unsigned u = __builtin_bit_cast(unsigned, f);
    return (unsigned short)((u + 0x7FFFu + ((u >> 16) & 1u)) >> 16);
}
static __device__ __forceinline__ float bf2f(unsigned short h) {
    unsigned u = ((unsigned)h) << 16;
    return __builtin_bit_cast(float, u);
}

// ---------------------------------------------------------------------------
// cast x (fp32) -> bf16, 8 elems/thread
// ---------------------------------------------------------------------------
__global__ __launch_bounds__(256)
void castx(const float* __restrict__ in, unsigned short* __restrict__ out) {
    size_t i = (size_t)blockIdx.x * 256 + threadIdx.x;   // 8-elem chunks
    const float4* p = (const float4*)in + 2 * i;
    float4 a = p[0], b = p[1];
    unsigned short tmp[8] = {f2bf(a.x), f2bf(a.y), f2bf(a.z), f2bf(a.w),
                             f2bf(b.x), f2bf(b.y), f2bf(b.z), f2bf(b.w)};
    ((uint4*)out)[i] = *(uint4*)tmp;
}

// ---------------------------------------------------------------------------
// W[K][N] fp32 -> Wt[N][K] bf16 (transpose+cast), 64x64 tiles
// ---------------------------------------------------------------------------
__global__ __launch_bounds__(256)
void wtrans(const float* __restrict__ W, unsigned short* __restrict__ Wt,
            int K, int N) {
    __shared__ float tile[64][65];
    int k0 = blockIdx.y * 64, n0 = blockIdx.x * 64;
    int t = threadIdx.x;
    #pragma unroll
    for (int i = 0; i < 4; ++i) {
        int f = t + 256 * i;           // 1024 float4 = 64 rows x 16 chunks
        int r = f >> 4, c4 = f & 15;
        float4 v = *(const float4*)(W + (size_t)(k0 + r) * N + n0 + c4 * 4);
        tile[r][c4 * 4 + 0] = v.x; tile[r][c4 * 4 + 1] = v.y;
        tile[r][c4 * 4 + 2] = v.z; tile[r][c4 * 4 + 3] = v.w;
    }
    __syncthreads();
    #pragma unroll
    for (int i = 0; i < 2; ++i) {
        int f = t + 256 * i;           // 512 chunks: 64 n-rows x 8 chunks of 8
        int r = f >> 3, c = f & 7;
        unsigned short tmp[8];
        #pragma unroll
        for (int j = 0; j < 8; ++j) tmp[j] = f2bf(tile[c * 8 + j][r]);
        *(uint4*)(Wt + (size_t)(n0 + r) * K + k0 + c * 8) = *(uint4*)tmp;
    }
}

// ---------------------------------------------------------------------------
// bf16 MFMA GEMM: C[M][N] = A[M][K] @ Bt[N][K]^T
// 128x128 tile, BK=64, 4 waves (2x2), 4x4 16x16x32 frags per wave.
// LDS rows 128B, XOR swizzle byte ^= ((row&7)<<4).
// ---------------------------------------------------------------------------
template <bool OUT_BF16>
__global__ __launch_bounds__(256)
void gemm_bf16(const unsigned short* __restrict__ A,
               const unsigned short* __restrict__ Bt,
               float* __restrict__ Cf, unsigned short* __restrict__ Cb,
               int M, int N, int K) {
    __shared__ unsigned short As[128 * 64];
    __shared__ unsigned short Bs[128 * 64];
    int t = threadIdx.x;
    int wid = t >> 6, lane = t & 63;
    int wm = wid >> 1, wn = wid & 1;
    int lr = lane & 15, lg = lane >> 4;
    int m0 = blockIdx.y * 128, n0 = blockIdx.x * 128;

    f32x4 acc[4][4];
    #pragma unroll
    for (int a = 0; a < 4; ++a)
        #pragma unroll
        for (int b = 0; b < 4; ++b)
            acc[a][b] = (f32x4){0.f, 0.f, 0.f, 0.f};

    for (int k0 = 0; k0 < K; k0 += 64) {
        #pragma unroll
        for (int i = 0; i < 4; ++i) {
            int f = t + 256 * i;       // 1024 16B chunks: 128 rows x 8
            int row = f >> 3, ch = f & 7;
            uint4 v = *(const uint4*)(A + (size_t)(m0 + row) * K + k0 + ch * 8);
            *(uint4*)((char*)As + row * 128 + ((ch * 16) ^ ((row & 7) << 4))) = v;
        }
        #pragma unroll
        for (int i = 0; i < 4; ++i) {
            int f = t + 256 * i;
            int row = f >> 3, ch = f & 7;
            uint4 v = *(const uint4*)(Bt + (size_t)(n0 + row) * K + k0 + ch * 8);
            *(uint4*)((char*)Bs + row * 128 + ((ch * 16) ^ ((row & 7) << 4))) = v;
        }
        __syncthreads();
        #pragma unroll
        for (int ks = 0; ks < 2; ++ks) {
            bf16x8 af[4], bfm[4];
            #pragma unroll
            for (int mb = 0; mb < 4; ++mb) {
                int row = wm * 64 + mb * 16 + lr;
                af[mb] = *(const bf16x8*)((const char*)As + row * 128 +
                          (((ks * 32 + lg * 8) * 2) ^ ((row & 7) << 4)));
            }
            #pragma unroll
            for (int nb = 0; nb < 4; ++nb) {
                int row = wn * 64 + nb * 16 + lr;
                bfm[nb] = *(const bf16x8*)((const char*)Bs + row * 128 +
                           (((ks * 32 + lg * 8) * 2) ^ ((row & 7) << 4)));
            }
            #pragma unroll
            for (int mb = 0; mb < 4; ++mb)
                #pragma unroll
                for (int nb = 0; nb < 4; ++nb)
                    acc[mb][nb] = __builtin_amdgcn_mfma_f32_16x16x32_bf16(
                        af[mb], bfm[nb], acc[mb][nb], 0, 0, 0);
        }
        __syncthreads();
    }
    // epilogue: D layout col=lane&15, row=4*(lane>>4)+reg
    #pragma unroll
    for (int mb = 0; mb < 4; ++mb)
        #pragma unroll
        for (int nb = 0; nb < 4; ++nb)
            #pragma unroll
            for (int r = 0; r < 4; ++r) {
                int row = m0 + wm * 64 + mb * 16 + lg * 4 + r;
                int col = n0 + wn * 64 + nb * 16 + lr;
                if (OUT_BF16)
                    Cb[(size_t)row * N + col] = f2bf(acc[mb][nb][r]);
                else
                    Cf[(size_t)row * N + col] = acc[mb][nb][r];
            }
}

// ---------------------------------------------------------------------------
// RoPE in-place on bf16 qkv (q,k halves). 8 dims (4 pairs) per thread.
// ---------------------------------------------------------------------------
__global__ __launch_bounds__(256)
void rope_qk(unsigned short* __restrict__ qkvb, const float* __restrict__ fc) {
    int gid = blockIdx.x * 256 + threadIdx.x;  // 4096*2*16*16 = 2097152
    int ch  = gid & 15;
    int h   = (gid >> 4) & 15;
    int sel = (gid >> 8) & 1;
    int row = gid >> 9;
    int t   = row & (T_ - 1);

    unsigned short* p = qkvb + (size_t)row * QKV_LD + sel * D_ + h * HD_ + ch * 8;
    uint4 v = *(uint4*)p;
    unsigned short* s = (unsigned short*)&v;
    const float* f = fc + ((size_t)t * 64 + ch * 4) * 2;
    float4 fA = *(const float4*)f;       // c0,s0,c1,s1
    float4 fB = *(const float4*)(f + 4); // c2,s2,c3,s3
    float x0 = bf2f(s[0]), x1 = bf2f(s[1]), x2 = bf2f(s[2]), x3 = bf2f(s[3]);
    float x4 = bf2f(s[4]), x5 = bf2f(s[5]), x6 = bf2f(s[6]), x7 = bf2f(s[7]);
    unsigned short o[8];
    o[0] = f2bf(x0 * fA.x - x1 * fA.y);
    o[1] = f2bf(x1 * fA.x + x0 * fA.y);
    o[2] = f2bf(x2 * fA.z - x3 * fA.w);
    o[3] = f2bf(x3 * fA.z + x2 * fA.w);
    o[4] = f2bf(x4 * fB.x - x5 * fB.y);
    o[5] = f2bf(x5 * fB.x + x4 * fB.y);
    o[6] = f2bf(x6 * fB.z - x7 * fB.w);
    o[7] = f2bf(x7 * fB.z + x6 * fB.w);
    *(uint4*)p = *(uint4*)o;
}

// ---------------------------------------------------------------------------
// Build vT[b][h][d][t] bf16 from qkv v-part. 64-t tile per block.
// ---------------------------------------------------------------------------
__global__ __launch_bounds__(256)
void vT_build(const unsigned short* __restrict__ qkvb,
              unsigned short* __restrict__ vT) {
    __shared__ unsigned short tile[128][72];
    int t0 = blockIdx.x * 64;
    int bh = blockIdx.y;
    int b = bh >> 4, h = bh & 15;
    int tid = threadIdx.x;
    #pragma unroll
    for (int i = 0; i < 4; ++i) {
        int f = tid + 256 * i;         // 1024 chunks: 64 t-rows x 16
        int tr = f >> 4, ch = f & 15;
        uint4 v = *(const uint4*)(qkvb +
            (size_t)(b * T_ + t0 + tr) * QKV_LD + 2 * D_ + h * HD_ + ch * 8);
        unsigned short* s = (unsigned short*)&v;
        #pragma unroll
        for (int j = 0; j < 8; ++j) tile[ch * 8 + j][tr] = s[j];
    }
    __syncthreads();
    #pragma unroll
    for (int i = 0; i < 4; ++i) {
        int f = tid + 256 * i;         // 1024 chunks: 128 d-rows x 8
        int d = f >> 3, ch = f & 7;
        uint4 v = *(uint4*)(&tile[d][ch * 8]);
        *(uint4*)(vT + ((size_t)(bh * 128 + d)) * T_ + t0 + ch * 8) = v;
    }
}

// ---------------------------------------------------------------------------
// MFMA flash attention (causal). QBLK=64, KVBLK=64, 4 waves x 16 q-rows.
// Swapped QK^T: mfma(K,Q) -> lane owns one q-row (col=lane&15).
// Outputs bf16 attnb[b*T+t][h*128+d].
// ---------------------------------------------------------------------------
__global__ __launch_bounds__(256)
void attn_mfma(const unsigned short* __restrict__ qkvb,
               const unsigned short* __restrict__ vT,
               unsigned short* __restrict__ attnb) {
    __shared__ unsigned short Qs[64 * 128];
    __shared__ unsigned short Ks[64 * 128];
    __shared__ unsigned short Vts[128 * 64];
    __shared__ unsigned short Ps[4 * 16 * 72];   // per-wave [16][72]

    int t = threadIdx.x;
    int wid = t >> 6, lane = t & 63;
    int lr = lane & 15, lg = lane >> 4;
    int qt = (int)gridDim.x - 1 - (int)blockIdx.x;  // heavy blocks first
    int bh = blockIdx.y;
    int b = bh >> 4, h = bh & 15;
    int qt0 = qt * 64;

    const unsigned short* qbase = qkvb + (size_t)(b * T_) * QKV_LD + h * HD_;
    const unsigned short* kbase = qbase + D_;
    const unsigned short* vbase = vT + (size_t)bh * 128 * T_;

    // stage Q (64 x 128), swizzled
    #pragma unroll
    for (int i = 0; i < 4; ++i) {
        int f = t + 256 * i;
        int row = f >> 4, ch = f & 15;
        uint4 v = *(const uint4*)(qbase + (size_t)(qt0 + row) * QKV_LD + ch * 8);
        *(uint4*)((char*)Qs + row * 256 + ((ch * 16) ^ ((row & 7) << 4))) = v;
    }

    f32x4 o[8];
    #pragma unroll
    for (int nb = 0; nb < 8; ++nb) o[nb] = (f32x4){0.f, 0.f, 0.f, 0.f};
    float m_r = -1e30f, l_r = 0.f;
    const int qrow_g = qt0 + wid * 16 + lr;   // this lane's q-row

    for (int kt = 0; kt <= qt; ++kt) {
        // stage K (64 x 128)
        #pragma unroll
        for (int i = 0; i < 4; ++i) {
            int f = t + 256 * i;
            int row = f >> 4, ch = f & 15;
            uint4 v = *(const uint4*)(kbase + (size_t)(kt * 64 + row) * QKV_LD + ch * 8);
            *(uint4*)((char*)Ks + row * 256 + ((ch * 16) ^ ((row & 7) << 4))) = v;
        }
        // stage Vt (128 d-rows x 64 keys)
        #pragma unroll
        for (int i = 0; i < 4; ++i) {
            int f = t + 256 * i;
            int row = f >> 3, ch = f & 7;
            uint4 v = *(const uint4*)(vbase + (size_t)row * T_ + kt * 64 + ch * 8);
            *(uint4*)((char*)Vts + row * 128 + ((ch * 16) ^ ((row & 7) << 4))) = v;
        }
        __syncthreads();

        // S^T = K @ Q^T : 4 key-blocks x 4 k-dim slices
        f32x4 s[4];
        #pragma unroll
        for (int kb = 0; kb < 4; ++kb) s[kb] = (f32x4){0.f, 0.f, 0.f, 0.f};
        #pragma unroll
        for (int kd = 0; kd < 4; ++kd) {
            int qrow = wid * 16 + lr;
            bf16x8 qf = *(const bf16x8*)((const char*)Qs + qrow * 256 +
                         (((kd * 32 + lg * 8) * 2) ^ ((qrow & 7) << 4)));
            #pragma unroll
            for (int kb = 0; kb < 4; ++kb) {
                int krow = kb * 16 + lr;
                bf16x8 kf = *(const bf16x8*)((const char*)Ks + krow * 256 +
                             (((kd * 32 + lg * 8) * 2) ^ ((krow & 7) << 4)));
                s[kb] = __builtin_amdgcn_mfma_f32_16x16x32_bf16(kf, qf, s[kb], 0, 0, 0);
            }
        }

        // scale + causal mask; per-lane online softmax (one q-row per lane)
        float sv[4][4];
        bool diag = (kt == qt);
        #pragma unroll
        for (int kb = 0; kb < 4; ++kb)
            #pragma unroll
            for (int r = 0; r < 4; ++r) {
                float v = s[kb][r] * SCALE;
                int key_g = kt * 64 + kb * 16 + 4 * lg + r;
                if (diag && key_g > qrow_g) v = -1e30f;
                sv[kb][r] = v;
            }
        float mt = -1e30f;
        #pragma unroll
        for (int kb = 0; kb < 4; ++kb)
            #pragma unroll
            for (int r = 0; r < 4; ++r) mt = fmaxf(mt, sv[kb][r]);
        mt = fmaxf(mt, __shfl_xor(mt, 16));
        mt = fmaxf(mt, __shfl_xor(mt, 32));
        float mnew = fmaxf(m_r, mt);
        float alpha = __expf(m_r - mnew);
        float psum = 0.f;
        unsigned pw[4][2];
        #pragma unroll
        for (int kb = 0; kb < 4; ++kb) {
            float p0 = __expf(sv[kb][0] - mnew);
            float p1 = __expf(sv[kb][1] - mnew);
            float p2 = __expf(sv[kb][2] - mnew);
            float p3 = __expf(sv[kb][3] - mnew);
            psum += p0 + p1 + p2 + p3;
            pw[kb][0] = (unsigned)f2bf(p0) | ((unsigned)f2bf(p1) << 16);
            pw[kb][1] = (unsigned)f2bf(p2) | ((unsigned)f2bf(p3) << 16);
        }
        psum += __shfl_xor(psum, 16);
        psum += __shfl_xor(psum, 32);
        l_r = l_r * alpha + psum;
        m_r = mnew;

        // rescale O (O rows = 4*lg + r; alpha lives in lane lr == row)
        float a0 = __shfl(alpha, 4 * lg + 0, 16);
        float a1 = __shfl(alpha, 4 * lg + 1, 16);
        float a2 = __shfl(alpha, 4 * lg + 2, 16);
        float a3 = __shfl(alpha, 4 * lg + 3, 16);
        #pragma unroll
        for (int nb = 0; nb < 8; ++nb) {
            o[nb][0] *= a0; o[nb][1] *= a1; o[nb][2] *= a2; o[nb][3] *= a3;
        }

        // write P (bf16) to per-wave LDS: [qrow=lr][key]
        unsigned short* pbase = Ps + wid * 1152 + lr * 72;
        #pragma unroll
        for (int kb = 0; kb < 4; ++kb) {
            uint2 w; w.x = pw[kb][0]; w.y = pw[kb][1];
            *(uint2*)(pbase + kb * 16 + 4 * lg) = w;
        }
        // PV: O += P(16x64) @ V(64x128); A=P rows=qrows, B=Vt rows=dims
        #pragma unroll
        for (int ks = 0; ks < 2; ++ks) {
            bf16x8 pa = *(const bf16x8*)(pbase + ks * 32 + 8 * lg);
            #pragma unroll
            for (int nb = 0; nb < 8; ++nb) {
                int vrow = nb * 16 + lr;
                bf16x8 vf = *(const bf16x8*)((const char*)Vts + vrow * 128 +
                             (((ks * 32 + lg * 8) * 2) ^ ((vrow & 7) << 4)));
                o[nb] = __builtin_amdgcn_mfma_f32_16x16x32_bf16(pa, vf, o[nb], 0, 0, 0);
            }
        }
        __syncthreads();
    }

    // epilogue: O/l, store bf16 to attnb[b*T+t][h*128+d]
    float linv = 1.0f / l_r;
    float li0 = __shfl(linv, 4 * lg + 0, 16);
    float li1 = __shfl(linv, 4 * lg + 1, 16);
    float li2 = __shfl(linv, 4 * lg + 2, 16);
    float li3 = __shfl(linv, 4 * lg + 3, 16);
    #pragma unroll
    for (int nb = 0; nb < 8; ++nb) {
        float li[4] = {li0, li1, li2, li3};
        #pragma unroll
        for (int r = 0; r < 4; ++r) {
            int trow = qt0 + wid * 16 + 4 * lg + r;
            attnb[((size_t)(b * T_ + trow)) * D_ + h * HD_ + nb * 16 + lr] =
                f2bf(o[nb][r] * li[r]);
        }
    }
}

// ---------------------------------------------------------------------------
// Launch
// ---------------------------------------------------------------------------
extern "C" void kernel_launch(void* const* d_in, const int* in_sizes, int n_in,
                              void* d_out, int out_size, void* d_ws, size_t ws_size,
                              hipStream_t stream) {
    const float* x    = (const float*)d_in[0];
    const float* Wqkv = (const float*)d_in[1];
    const float* Wout = (const float*)d_in[2];
    const float* fc   = (const float*)d_in[3];
    float* out = (float*)d_out;

    char* ws = (char*)d_ws;
    unsigned short* xb    = (unsigned short*)(ws);                  // 16 MB (aliased w/ attnb)
    unsigned short* attnb = xb;
    unsigned short* WqkvT = (unsigned short*)(ws + 16777216);       // 24 MB
    unsigned short* WoutT = (unsigned short*)(ws + 41943040);       // 8 MB
    unsigned short* qkvb  = (unsigned short*)(ws + 50331648);       // 48 MB
    unsigned short* vT    = (unsigned short*)(ws + 100663296);      // 16 MB -> ends 112 MB

    dim3 blk(256);

    castx<<<4096, blk, 0, stream>>>(x, xb);                              // 4096*2048/8
    wtrans<<<dim3(96, 32), blk, 0, stream>>>(Wqkv, WqkvT, 2048, 6144);
    wtrans<<<dim3(32, 32), blk, 0, stream>>>(Wout, WoutT, 2048, 2048);

    // qkv (bf16) = x @ Wqkv
    gemm_bf16<true><<<dim3(48, 32), blk, 0, stream>>>(xb, WqkvT, nullptr, qkvb,
                                                      4096, 6144, 2048);
    rope_qk<<<8192, blk, 0, stream>>>(qkvb, fc);
    vT_build<<<dim3(32, 32), blk, 0, stream>>>(qkvb, vT);
    attn_mfma<<<dim3(32, 32), blk, 0, stream>>>(qkvb, vT, attnb);
    // out (fp32) = attn @ Wout
    gemm_bf16<false><<<dim3(16, 32), blk, 0, stream>>>(attnb, WoutT, out, nullptr,
                                                       4096, 2048, 2048);
}

// Round 6
// 424.195 us; speedup vs baseline: 8.9557x; 1.1093x over previous
//
#include <hip/hip_runtime.h>
#include <math.h>

// Problem constants
#define B_   2
#define T_   2048
#define D_   2048
#define H_   16
#define HD_  128
#define QKV_LD 6144
#define SCALE 0.08838834764831845f  // 1/sqrt(128)

typedef __attribute__((ext_vector_type(4))) float f32x4;
typedef __attribute__((ext_vector_type(8))) short bf16x8;

static __device__ __forceinline__ unsigned short f2bf(float f) {
    unsigned u = __builtin_bit_cast(unsigned, f);
    return (unsigned short)((u + 0x7FFFu + ((u >> 16) & 1u)) >> 16);
}
static __device__ __forceinline__ float bf2f(unsigned short h) {
    unsigned u = ((unsigned)h) << 16;
    return __builtin_bit_cast(float, u);
}

// async global->LDS DMA, 16B per lane. LDS dest must be wave-uniform base
// (HW writes base + lane*16); global src is per-lane.
static __device__ __forceinline__ void gload_lds16(const void* g, void* l) {
    __builtin_amdgcn_global_load_lds(
        (const __attribute__((address_space(1))) unsigned int*)g,
        (__attribute__((address_space(3))) unsigned int*)l, 16, 0, 0);
}

// ---------------------------------------------------------------------------
// cast x (fp32) -> bf16, 8 elems/thread
// ---------------------------------------------------------------------------
__global__ __launch_bounds__(256)
void castx(const float* __restrict__ in, unsigned short* __restrict__ out) {
    size_t i = (size_t)blockIdx.x * 256 + threadIdx.x;   // 8-elem chunks
    const float4* p = (const float4*)in + 2 * i;
    float4 a = p[0], b = p[1];
    unsigned short tmp[8] = {f2bf(a.x), f2bf(a.y), f2bf(a.z), f2bf(a.w),
                             f2bf(b.x), f2bf(b.y), f2bf(b.z), f2bf(b.w)};
    ((uint4*)out)[i] = *(uint4*)tmp;
}

// ---------------------------------------------------------------------------
// W[K][N] fp32 -> Wt[N][K] bf16 (transpose+cast), 64x64 tiles
// ---------------------------------------------------------------------------
__global__ __launch_bounds__(256)
void wtrans(const float* __restrict__ W, unsigned short* __restrict__ Wt,
            int K, int N) {
    __shared__ float tile[64][65];
    int k0 = blockIdx.y * 64, n0 = blockIdx.x * 64;
    int t = threadIdx.x;
    #pragma unroll
    for (int i = 0; i < 4; ++i) {
        int f = t + 256 * i;
        int r = f >> 4, c4 = f & 15;
        float4 v = *(const float4*)(W + (size_t)(k0 + r) * N + n0 + c4 * 4);
        tile[r][c4 * 4 + 0] = v.x; tile[r][c4 * 4 + 1] = v.y;
        tile[r][c4 * 4 + 2] = v.z; tile[r][c4 * 4 + 3] = v.w;
    }
    __syncthreads();
    #pragma unroll
    for (int i = 0; i < 2; ++i) {
        int f = t + 256 * i;
        int r = f >> 3, c = f & 7;
        unsigned short tmp[8];
        #pragma unroll
        for (int j = 0; j < 8; ++j) tmp[j] = f2bf(tile[c * 8 + j][r]);
        *(uint4*)(Wt + (size_t)(n0 + r) * K + k0 + c * 8) = *(uint4*)tmp;
    }
}

// ---------------------------------------------------------------------------
// bf16 MFMA GEMM (m97 structure): C[M][N] = A[M][K] @ Bt[N][K]^T
// 128x128 tile, BK=64, 4 waves, global_load_lds w=16 with pre-swizzled
// source so reads keep the XOR swizzle (linear dest + inv-swz src).
// ---------------------------------------------------------------------------
template <bool OUT_BF16>
__global__ __launch_bounds__(256)
void gemm_bf16(const unsigned short* __restrict__ A,
               const unsigned short* __restrict__ Bt,
               float* __restrict__ Cf, unsigned short* __restrict__ Cb,
               int M, int N, int K) {
    __shared__ unsigned short As[128 * 64];
    __shared__ unsigned short Bs[128 * 64];
    int t = threadIdx.x;
    int wid = t >> 6, lane = t & 63;
    int wm = wid >> 1, wn = wid & 1;
    int lr = lane & 15, lg = lane >> 4;

    // XCD-aware swizzle (grid size divisible by 8 for all our launches)
    int nwg = gridDim.x * gridDim.y;
    int wg  = blockIdx.y * gridDim.x + blockIdx.x;
    int wgs = (wg & 7) * (nwg >> 3) + (wg >> 3);
    int m0 = (wgs / gridDim.x) * 128;
    int n0 = (wgs % gridDim.x) * 128;

    f32x4 acc[4][4];
    #pragma unroll
    for (int a = 0; a < 4; ++a)
        #pragma unroll
        for (int b = 0; b < 4; ++b)
            acc[a][b] = (f32x4){0.f, 0.f, 0.f, 0.f};

    for (int k0 = 0; k0 < K; k0 += 64) {
        // stage A,B tiles: 1024 chunks each; wave-uniform LDS base, per-lane
        // global src with inverse swizzle ch = chL ^ (row&7)
        #pragma unroll
        for (int i = 0; i < 4; ++i) {
            int c = (wid * 4 + i) * 64 + lane;
            int row = c >> 3, ch = (c & 7) ^ (row & 7);
            gload_lds16(A + (size_t)(m0 + row) * K + k0 + ch * 8,
                        (char*)As + (wid * 4 + i) * 1024);
            gload_lds16(Bt + (size_t)(n0 + row) * K + k0 + ch * 8,
                        (char*)Bs + (wid * 4 + i) * 1024);
        }
        __syncthreads();
        #pragma unroll
        for (int ks = 0; ks < 2; ++ks) {
            bf16x8 af[4], bfm[4];
            #pragma unroll
            for (int mb = 0; mb < 4; ++mb) {
                int row = wm * 64 + mb * 16 + lr;
                af[mb] = *(const bf16x8*)((const char*)As + row * 128 +
                          (((ks * 32 + lg * 8) * 2) ^ ((row & 7) << 4)));
            }
            #pragma unroll
            for (int nb = 0; nb < 4; ++nb) {
                int row = wn * 64 + nb * 16 + lr;
                bfm[nb] = *(const bf16x8*)((const char*)Bs + row * 128 +
                           (((ks * 32 + lg * 8) * 2) ^ ((row & 7) << 4)));
            }
            #pragma unroll
            for (int mb = 0; mb < 4; ++mb)
                #pragma unroll
                for (int nb = 0; nb < 4; ++nb)
                    acc[mb][nb] = __builtin_amdgcn_mfma_f32_16x16x32_bf16(
                        af[mb], bfm[nb], acc[mb][nb], 0, 0, 0);
        }
        __syncthreads();
    }
    #pragma unroll
    for (int mb = 0; mb < 4; ++mb)
        #pragma unroll
        for (int nb = 0; nb < 4; ++nb)
            #pragma unroll
            for (int r = 0; r < 4; ++r) {
                int row = m0 + wm * 64 + mb * 16 + lg * 4 + r;
                int col = n0 + wn * 64 + nb * 16 + lr;
                if (OUT_BF16)
                    Cb[(size_t)row * N + col] = f2bf(acc[mb][nb][r]);
                else
                    Cf[(size_t)row * N + col] = acc[mb][nb][r];
            }
}

// ---------------------------------------------------------------------------
// RoPE in-place on bf16 qkv (q,k halves). 8 dims (4 pairs) per thread.
// ---------------------------------------------------------------------------
__global__ __launch_bounds__(256)
void rope_qk(unsigned short* __restrict__ qkvb, const float* __restrict__ fc) {
    int gid = blockIdx.x * 256 + threadIdx.x;
    int ch  = gid & 15;
    int h   = (gid >> 4) & 15;
    int sel = (gid >> 8) & 1;
    int row = gid >> 9;
    int t   = row & (T_ - 1);

    unsigned short* p = qkvb + (size_t)row * QKV_LD + sel * D_ + h * HD_ + ch * 8;
    uint4 v = *(uint4*)p;
    unsigned short* s = (unsigned short*)&v;
    const float* f = fc + ((size_t)t * 64 + ch * 4) * 2;
    float4 fA = *(const float4*)f;
    float4 fB = *(const float4*)(f + 4);
    float x0 = bf2f(s[0]), x1 = bf2f(s[1]), x2 = bf2f(s[2]), x3 = bf2f(s[3]);
    float x4 = bf2f(s[4]), x5 = bf2f(s[5]), x6 = bf2f(s[6]), x7 = bf2f(s[7]);
    unsigned short o[8];
    o[0] = f2bf(x0 * fA.x - x1 * fA.y);
    o[1] = f2bf(x1 * fA.x + x0 * fA.y);
    o[2] = f2bf(x2 * fA.z - x3 * fA.w);
    o[3] = f2bf(x3 * fA.z + x2 * fA.w);
    o[4] = f2bf(x4 * fB.x - x5 * fB.y);
    o[5] = f2bf(x5 * fB.x + x4 * fB.y);
    o[6] = f2bf(x6 * fB.z - x7 * fB.w);
    o[7] = f2bf(x7 * fB.z + x6 * fB.w);
    *(uint4*)p = *(uint4*)o;
}

// ---------------------------------------------------------------------------
// Build vT[b][h][d][t] bf16 from qkv v-part. 64-t tile per block.
// ---------------------------------------------------------------------------
__global__ __launch_bounds__(256)
void vT_build(const unsigned short* __restrict__ qkvb,
              unsigned short* __restrict__ vT) {
    __shared__ unsigned short tile[128][72];
    int t0 = blockIdx.x * 64;
    int bh = blockIdx.y;
    int b = bh >> 4, h = bh & 15;
    int tid = threadIdx.x;
    #pragma unroll
    for (int i = 0; i < 4; ++i) {
        int f = tid + 256 * i;
        int tr = f >> 4, ch = f & 15;
        uint4 v = *(const uint4*)(qkvb +
            (size_t)(b * T_ + t0 + tr) * QKV_LD + 2 * D_ + h * HD_ + ch * 8);
        unsigned short* s = (unsigned short*)&v;
        #pragma unroll
        for (int j = 0; j < 8; ++j) tile[ch * 8 + j][tr] = s[j];
    }
    __syncthreads();
    #pragma unroll
    for (int i = 0; i < 4; ++i) {
        int f = tid + 256 * i;
        int d = f >> 3, ch = f & 7;
        uint4 v = *(uint4*)(&tile[d][ch * 8]);
        *(uint4*)(vT + ((size_t)(bh * 128 + d)) * T_ + t0 + ch * 8) = v;
    }
}

// ---------------------------------------------------------------------------
// MFMA flash attention (causal), double-buffered K/V via global_load_lds.
// QBLK=64, KVBLK=64, 4 waves x 16 q-rows. Swapped QK^T (lane owns a q-row).
// One barrier per K-tile; prefetch issued before compute (T3-minimum).
// Q-frags hoisted; Ps aliases Qs; setprio around MFMA; defer-max (THR=8).
// ---------------------------------------------------------------------------
__global__ __launch_bounds__(256)
void attn_mfma(const unsigned short* __restrict__ qkvb,
               const unsigned short* __restrict__ vT,
               unsigned short* __restrict__ attnb) {
    __shared__ unsigned short Qs[64 * 128];      // reused as Ps after hoist
    __shared__ unsigned short Ks[2][64 * 128];
    __shared__ unsigned short Vts[2][128 * 64];

    int t = threadIdx.x;
    int wid = t >> 6, lane = t & 63;
    int lr = lane & 15, lg = lane >> 4;

    // XCD-chunked swizzle: each XCD gets 4 consecutive bh (K/V = 4MB = L2),
    // heavy q-tiles first within each bh. 1024 % 8 == 0 -> bijective.
    int wg  = blockIdx.x;
    int wgs = (wg & 7) * 128 + (wg >> 3);
    int bh  = wgs >> 5;
    int qt  = 31 - (wgs & 31);
    int b = bh >> 4, h = bh & 15;
    int qt0 = qt * 64;

    const unsigned short* qbase = qkvb + (size_t)(b * T_) * QKV_LD + h * HD_;
    const unsigned short* kbase = qbase + D_;
    const unsigned short* vbase = vT + (size_t)bh * 128 * T_;

    // prologue: stage Q + K/V tile 0 (async DMA, pre-swizzled source)
    #pragma unroll
    for (int i = 0; i < 4; ++i) {
        int c = (wid * 4 + i) * 64 + lane;
        int row = c >> 4, ch = (c & 15) ^ (row & 7);
        gload_lds16(qbase + (size_t)(qt0 + row) * QKV_LD + ch * 8,
                    (char*)Qs + (wid * 4 + i) * 1024);
    }
    #pragma unroll
    for (int i = 0; i < 4; ++i) {
        int c = (wid * 4 + i) * 64 + lane;
        int rowk = c >> 4, chk = (c & 15) ^ (rowk & 7);
        gload_lds16(kbase + (size_t)rowk * QKV_LD + chk * 8,
                    (char*)Ks[0] + (wid * 4 + i) * 1024);
        int rowv = c >> 3, chv = (c & 7) ^ (rowv & 7);
        gload_lds16(vbase + (size_t)rowv * T_ + chv * 8,
                    (char*)Vts[0] + (wid * 4 + i) * 1024);
    }
    __syncthreads();

    // hoist loop-invariant Q fragments
    bf16x8 qf[4];
    {
        int qrow = wid * 16 + lr;
        #pragma unroll
        for (int kd = 0; kd < 4; ++kd)
            qf[kd] = *(const bf16x8*)((const char*)Qs + qrow * 256 +
                       (((kd * 32 + lg * 8) * 2) ^ ((qrow & 7) << 4)));
    }
    __syncthreads();   // all waves hoisted Q before Ps (=Qs) is overwritten
    unsigned short* Ps = Qs;   // per-wave [16][72]

    f32x4 o[8];
    #pragma unroll
    for (int nb = 0; nb < 8; ++nb) o[nb] = (f32x4){0.f, 0.f, 0.f, 0.f};
    float m_r = -1e30f, l_r = 0.f;
    const int qrow_g = qt0 + wid * 16 + lr;

    for (int kt = 0; kt <= qt; ++kt) {
        int cur = kt & 1;
        // prefetch next tile into the other buffer (drained at the barrier)
        if (kt < qt) {
            #pragma unroll
            for (int i = 0; i < 4; ++i) {
                int c = (wid * 4 + i) * 64 + lane;
                int rowk = c >> 4, chk = (c & 15) ^ (rowk & 7);
                gload_lds16(kbase + (size_t)((kt + 1) * 64 + rowk) * QKV_LD + chk * 8,
                            (char*)Ks[cur ^ 1] + (wid * 4 + i) * 1024);
                int rowv = c >> 3, chv = (c & 7) ^ (rowv & 7);
                gload_lds16(vbase + (size_t)rowv * T_ + (kt + 1) * 64 + chv * 8,
                            (char*)Vts[cur ^ 1] + (wid * 4 + i) * 1024);
            }
        }
        const unsigned short* Kc = Ks[cur];
        const unsigned short* Vc = Vts[cur];

        // S^T = K @ Q^T
        f32x4 s[4];
        #pragma unroll
        for (int kb = 0; kb < 4; ++kb) s[kb] = (f32x4){0.f, 0.f, 0.f, 0.f};
        __builtin_amdgcn_s_setprio(1);
        #pragma unroll
        for (int kd = 0; kd < 4; ++kd) {
            #pragma unroll
            for (int kb = 0; kb < 4; ++kb) {
                int krow = kb * 16 + lr;
                bf16x8 kf = *(const bf16x8*)((const char*)Kc + krow * 256 +
                             (((kd * 32 + lg * 8) * 2) ^ ((krow & 7) << 4)));
                s[kb] = __builtin_amdgcn_mfma_f32_16x16x32_bf16(kf, qf[kd], s[kb], 0, 0, 0);
            }
        }
        __builtin_amdgcn_s_setprio(0);

        // scale + causal mask; per-lane online softmax
        float sv[4][4];
        bool diag = (kt == qt);
        #pragma unroll
        for (int kb = 0; kb < 4; ++kb)
            #pragma unroll
            for (int r = 0; r < 4; ++r) {
                float v = s[kb][r] * SCALE;
                int key_g = kt * 64 + kb * 16 + 4 * lg + r;
                if (diag && key_g > qrow_g) v = -1e30f;
                sv[kb][r] = v;
            }
        float mt = -1e30f;
        #pragma unroll
        for (int kb = 0; kb < 4; ++kb)
            #pragma unroll
            for (int r = 0; r < 4; ++r) mt = fmaxf(mt, sv[kb][r]);
        mt = fmaxf(mt, __shfl_xor(mt, 16));
        mt = fmaxf(mt, __shfl_xor(mt, 32));

        // defer-max (T13): skip rescale while tile max stays within THR=8
        bool defer = __all(mt - m_r <= 8.0f) != 0;
        float mnew  = defer ? m_r : fmaxf(m_r, mt);
        float alpha = defer ? 1.0f : __expf(m_r - mnew);

        float psum = 0.f;
        unsigned pw[4][2];
        #pragma unroll
        for (int kb = 0; kb < 4; ++kb) {
            float p0 = __expf(sv[kb][0] - mnew);
            float p1 = __expf(sv[kb][1] - mnew);
            float p2 = __expf(sv[kb][2] - mnew);
            float p3 = __expf(sv[kb][3] - mnew);
            psum += p0 + p1 + p2 + p3;
            pw[kb][0] = (unsigned)f2bf(p0) | ((unsigned)f2bf(p1) << 16);
            pw[kb][1] = (unsigned)f2bf(p2) | ((unsigned)f2bf(p3) << 16);
        }
        psum += __shfl_xor(psum, 16);
        psum += __shfl_xor(psum, 32);
        l_r = l_r * alpha + psum;
        m_r = mnew;

        if (!defer) {   // wave-uniform branch
            float a0 = __shfl(alpha, 4 * lg + 0, 16);
            float a1 = __shfl(alpha, 4 * lg + 1, 16);
            float a2 = __shfl(alpha, 4 * lg + 2, 16);
            float a3 = __shfl(alpha, 4 * lg + 3, 16);
            #pragma unroll
            for (int nb = 0; nb < 8; ++nb) {
                o[nb][0] *= a0; o[nb][1] *= a1; o[nb][2] *= a2; o[nb][3] *= a3;
            }
        }

        // write P (bf16) to per-wave LDS slice
        unsigned short* pbase = Ps + wid * 1152 + lr * 72;
        #pragma unroll
        for (int kb = 0; kb < 4; ++kb) {
            uint2 w; w.x = pw[kb][0]; w.y = pw[kb][1];
            *(uint2*)(pbase + kb * 16 + 4 * lg) = w;
        }
        // PV: O += P(16x64) @ V(64x128)
        __builtin_amdgcn_s_setprio(1);
        #pragma unroll
        for (int ks = 0; ks < 2; ++ks) {
            bf16x8 pa = *(const bf16x8*)(pbase + ks * 32 + 8 * lg);
            #pragma unroll
            for (int nb = 0; nb < 8; ++nb) {
                int vrow = nb * 16 + lr;
                bf16x8 vf = *(const bf16x8*)((const char*)Vc + vrow * 128 +
                             (((ks * 32 + lg * 8) * 2) ^ ((vrow & 7) << 4)));
                o[nb] = __builtin_amdgcn_mfma_f32_16x16x32_bf16(pa, vf, o[nb], 0, 0, 0);
            }
        }
        __builtin_amdgcn_s_setprio(0);
        __syncthreads();   // drains prefetch (vmcnt) + LDS; next buffer ready
    }

    // epilogue
    float linv = 1.0f / l_r;
    float li0 = __shfl(linv, 4 * lg + 0, 16);
    float li1 = __shfl(linv, 4 * lg + 1, 16);
    float li2 = __shfl(linv, 4 * lg + 2, 16);
    float li3 = __shfl(linv, 4 * lg + 3, 16);
    #pragma unroll
    for (int nb = 0; nb < 8; ++nb) {
        float li[4] = {li0, li1, li2, li3};
        #pragma unroll
        for (int r = 0; r < 4; ++r) {
            int trow = qt0 + wid * 16 + 4 * lg + r;
            attnb[((size_t)(b * T_ + trow)) * D_ + h * HD_ + nb * 16 + lr] =
                f2bf(o[nb][r] * li[r]);
        }
    }
}

// ---------------------------------------------------------------------------
// Launch
// ---------------------------------------------------------------------------
extern "C" void kernel_launch(void* const* d_in, const int* in_sizes, int n_in,
                              void* d_out, int out_size, void* d_ws, size_t ws_size,
                              hipStream_t stream) {
    const float* x    = (const float*)d_in[0];
    const float* Wqkv = (const float*)d_in[1];
    const float* Wout = (const float*)d_in[2];
    const float* fc   = (const float*)d_in[3];
    float* out = (float*)d_out;

    char* ws = (char*)d_ws;
    unsigned short* xb    = (unsigned short*)(ws);                  // 16 MB (aliased w/ attnb)
    unsigned short* attnb = xb;
    unsigned short* WqkvT = (unsigned short*)(ws + 16777216);       // 24 MB
    unsigned short* WoutT = (unsigned short*)(ws + 41943040);       // 8 MB
    unsigned short* qkvb  = (unsigned short*)(ws + 50331648);       // 48 MB
    unsigned short* vT    = (unsigned short*)(ws + 100663296);      // 16 MB -> ends 112 MB

    dim3 blk(256);

    castx<<<4096, blk, 0, stream>>>(x, xb);
    wtrans<<<dim3(96, 32), blk, 0, stream>>>(Wqkv, WqkvT, 2048, 6144);
    wtrans<<<dim3(32, 32), blk, 0, stream>>>(Wout, WoutT, 2048, 2048);

    // qkv (bf16) = x @ Wqkv
    gemm_bf16<true><<<dim3(48, 32), blk, 0, stream>>>(xb, WqkvT, nullptr, qkvb,
                                                      4096, 6144, 2048);
    rope_qk<<<8192, blk, 0, stream>>>(qkvb, fc);
    vT_build<<<dim3(32, 32), blk, 0, stream>>>(qkvb, vT);
    attn_mfma<<<1024, blk, 0, stream>>>(qkvb, vT, attnb);
    // out (fp32) = attn @ Wout
    gemm_bf16<false><<<dim3(16, 32), blk, 0, stream>>>(attnb, WoutT, out, nullptr,
                                                       4096, 2048, 2048);
}

// Round 8
// 423.478 us; speedup vs baseline: 8.9709x; 1.0017x over previous
//
#include <hip/hip_runtime.h>
#include <math.h>

// Problem constants
#define B_   2
#define T_   2048
#define D_   2048
#define H_   16
#define HD_  128
#define QKV_LD 6144
#define SCALE 0.08838834764831845f  // 1/sqrt(128)

typedef __attribute__((ext_vector_type(4))) float f32x4;
typedef __attribute__((ext_vector_type(8))) short bf16x8;

static __device__ __forceinline__ unsigned short f2bf(float f) {
    unsigned u = __builtin_bit_cast(unsigned, f);
    return (unsigned short)((u + 0x7FFFu + ((u >> 16) & 1u)) >> 16);
}
static __device__ __forceinline__ float bf2f(unsigned short h) {
    unsigned u = ((unsigned)h) << 16;
    return __builtin_bit_cast(float, u);
}

// async global->LDS DMA, 16B per lane. LDS dest is wave-uniform base
// (HW writes base + lane*16); global src is per-lane.
static __device__ __forceinline__ void gload_lds16(const void* g, void* l) {
    __builtin_amdgcn_global_load_lds(
        (const __attribute__((address_space(1))) unsigned int*)g,
        (__attribute__((address_space(3))) unsigned int*)l, 16, 0, 0);
}

// ---------------------------------------------------------------------------
// cast x (fp32) -> bf16, 8 elems/thread
// ---------------------------------------------------------------------------
__global__ __launch_bounds__(256)
void castx(const float* __restrict__ in, unsigned short* __restrict__ out) {
    size_t i = (size_t)blockIdx.x * 256 + threadIdx.x;
    const float4* p = (const float4*)in + 2 * i;
    float4 a = p[0], b = p[1];
    unsigned short tmp[8] = {f2bf(a.x), f2bf(a.y), f2bf(a.z), f2bf(a.w),
                             f2bf(b.x), f2bf(b.y), f2bf(b.z), f2bf(b.w)};
    ((uint4*)out)[i] = *(uint4*)tmp;
}

// ---------------------------------------------------------------------------
// W[K][N] fp32 -> Wt[N][K] bf16 (transpose+cast), 64x64 tiles
// ---------------------------------------------------------------------------
__global__ __launch_bounds__(256)
void wtrans(const float* __restrict__ W, unsigned short* __restrict__ Wt,
            int K, int N) {
    __shared__ float tile[64][65];
    int k0 = blockIdx.y * 64, n0 = blockIdx.x * 64;
    int t = threadIdx.x;
    #pragma unroll
    for (int i = 0; i < 4; ++i) {
        int f = t + 256 * i;
        int r = f >> 4, c4 = f & 15;
        float4 v = *(const float4*)(W + (size_t)(k0 + r) * N + n0 + c4 * 4);
        tile[r][c4 * 4 + 0] = v.x; tile[r][c4 * 4 + 1] = v.y;
        tile[r][c4 * 4 + 2] = v.z; tile[r][c4 * 4 + 3] = v.w;
    }
    __syncthreads();
    #pragma unroll
    for (int i = 0; i < 2; ++i) {
        int f = t + 256 * i;
        int r = f >> 3, c = f & 7;
        unsigned short tmp[8];
        #pragma unroll
        for (int j = 0; j < 8; ++j) tmp[j] = f2bf(tile[c * 8 + j][r]);
        *(uint4*)(Wt + (size_t)(n0 + r) * K + k0 + c * 8) = *(uint4*)tmp;
    }
}

// ---------------------------------------------------------------------------
// bf16 MFMA GEMM, counted-vmcnt phase pipeline (T3+T4):
// C[M][N] = A[M][K] @ Bt[N][K]^T. BM=256, BN=128, BK=64.
// 8 waves (2M x 4N), wave tile 128x32, acc 8x2 f32x4.
// Triple-buffered LDS (stage tile t+2 while computing t; DMA never targets a
// buffer with live readers). vmcnt(6) once per K-tile (never 0 mid-loop);
// raw s_barrier (no implicit drain); setprio around MFMA clusters.
// XOR swizzle via pre-swizzled global source + swizzled ds_read (rule #21).
// ---------------------------------------------------------------------------
template <bool OUT_BF16>
__global__ __launch_bounds__(512, 2)
void gemm_p2(const unsigned short* __restrict__ A,
             const unsigned short* __restrict__ Bt,
             float* __restrict__ Cf, unsigned short* __restrict__ Cb,
             int M, int N, int K) {
    __shared__ unsigned short As[3][256 * 64];   // 3 x 32 KB
    __shared__ unsigned short Bs[3][128 * 64];   // 3 x 16 KB

    const int t = threadIdx.x;
    const int wid = t >> 6, lane = t & 63;
    const int wm = wid >> 2, wn = wid & 3;       // 2 x 4 wave grid
    const int lr = lane & 15, lg = lane >> 4;

    // XCD-aware bijective swizzle (nwg % 8 == 0 for all our launches)
    const int gx  = N >> 7;                      // N / 128
    const int nwg = gridDim.x;
    const int wg  = blockIdx.x;
    const int wgs = (wg & 7) * (nwg >> 3) + (wg >> 3);
    const int m0  = (wgs / gx) * 256;
    const int n0  = (wgs % gx) * 128;

    const int nt = K >> 6;

    // staging lambdas: linear LDS dest (1KB per wave-issue), inv-swz source
    const int sr  = lane >> 3;                   // row within 8-row group
    const int sc  = lane & 7;                    // 16B chunk
    auto stageA = [&](int kt, int buf) {
        const unsigned short* src = A + (size_t)m0 * K + kt * 64;
        #pragma unroll
        for (int j = 0; j < 4; ++j) {
            int r = (wid * 4 + j) * 8 + sr;      // 0..255
            int ch = sc ^ (r & 7);
            gload_lds16(src + (size_t)r * K + ch * 8,
                        (char*)As[buf] + (wid * 4 + j) * 1024);
        }
    };
    auto stageB = [&](int kt, int buf) {
        const unsigned short* src = Bt + (size_t)n0 * K + kt * 64;
        #pragma unroll
        for (int j = 0; j < 2; ++j) {
            int r = (wid * 2 + j) * 8 + sr;      // 0..127
            int ch = sc ^ (r & 7);
            gload_lds16(src + (size_t)r * K + ch * 8,
                        (char*)Bs[buf] + (wid * 2 + j) * 1024);
        }
    };
    auto ldA = [&](int buf, int mb, int ks) -> bf16x8 {
        int row = wm * 128 + mb * 16 + lr;
        return *(const bf16x8*)((const char*)As[buf] + row * 128 +
                (((ks * 32 + lg * 8) * 2) ^ ((row & 7) << 4)));
    };
    auto ldB = [&](int buf, int nb, int ks) -> bf16x8 {
        int row = wn * 32 + nb * 16 + lr;
        return *(const bf16x8*)((const char*)Bs[buf] + row * 128 +
                (((ks * 32 + lg * 8) * 2) ^ ((row & 7) << 4)));
    };

    f32x4 acc[8][2];
    #pragma unroll
    for (int mb = 0; mb < 8; ++mb)
        #pragma unroll
        for (int nb = 0; nb < 2; ++nb)
            acc[mb][nb] = (f32x4){0.f, 0.f, 0.f, 0.f};

    // prologue: stage tiles 0 and 1; wait for tile 0 only (6 left in flight)
    stageA(0, 0); stageB(0, 0);
    stageA(1, 1); stageB(1, 1);
    asm volatile("s_waitcnt vmcnt(6)" ::: "memory");
    __builtin_amdgcn_s_barrier();

    for (int kt = 0; kt < nt; ++kt) {
        const int buf  = kt % 3;
        const int nbuf = (kt + 2) % 3;
        const bool pf  = (kt + 2) < nt;

        // ---- phase 0: mb 0-3 (all nb, ks) ----
        bf16x8 a0[4][2], bb[2][2];
        #pragma unroll
        for (int mb = 0; mb < 4; ++mb)
            #pragma unroll
            for (int ks = 0; ks < 2; ++ks) a0[mb][ks] = ldA(buf, mb, ks);
        #pragma unroll
        for (int nb = 0; nb < 2; ++nb)
            #pragma unroll
            for (int ks = 0; ks < 2; ++ks) bb[nb][ks] = ldB(buf, nb, ks);
        if (pf) stageA(kt + 2, nbuf);
        __builtin_amdgcn_s_barrier();
        __builtin_amdgcn_sched_barrier(0);
        __builtin_amdgcn_s_setprio(1);
        #pragma unroll
        for (int mb = 0; mb < 4; ++mb)
            #pragma unroll
            for (int nb = 0; nb < 2; ++nb)
                #pragma unroll
                for (int ks = 0; ks < 2; ++ks)
                    acc[mb][nb] = __builtin_amdgcn_mfma_f32_16x16x32_bf16(
                        a0[mb][ks], bb[nb][ks], acc[mb][nb], 0, 0, 0);
        __builtin_amdgcn_s_setprio(0);
        __builtin_amdgcn_s_barrier();

        // ---- phase 1: mb 4-7 (B frags reused from registers) ----
        bf16x8 a1[4][2];
        #pragma unroll
        for (int mb = 0; mb < 4; ++mb)
            #pragma unroll
            for (int ks = 0; ks < 2; ++ks) a1[mb][ks] = ldA(buf, mb + 4, ks);
        if (pf) stageB(kt + 2, nbuf);
        __builtin_amdgcn_s_barrier();
        __builtin_amdgcn_sched_barrier(0);
        __builtin_amdgcn_s_setprio(1);
        #pragma unroll
        for (int mb = 0; mb < 4; ++mb)
            #pragma unroll
            for (int nb = 0; nb < 2; ++nb)
                #pragma unroll
                for (int ks = 0; ks < 2; ++ks)
                    acc[mb + 4][nb] = __builtin_amdgcn_mfma_f32_16x16x32_bf16(
                        a1[mb][ks], bb[nb][ks], acc[mb + 4][nb], 0, 0, 0);
        __builtin_amdgcn_s_setprio(0);
        // end-of-tile: ensure tile kt+1 fully landed before its reads;
        // keep tile kt+2's 6 issues in flight (counted, never 0 mid-loop)
        if (kt + 2 < nt) {
            asm volatile("s_waitcnt vmcnt(6)" ::: "memory");
        } else if (kt + 1 < nt) {
            asm volatile("s_waitcnt vmcnt(0)" ::: "memory");
        }
        __builtin_amdgcn_s_barrier();
    }

    // epilogue: D layout col=lane&15, row=4*(lane>>4)+reg
    #pragma unroll
    for (int mb = 0; mb < 8; ++mb)
        #pragma unroll
        for (int nb = 0; nb < 2; ++nb)
            #pragma unroll
            for (int r = 0; r < 4; ++r) {
                int row = m0 + wm * 128 + mb * 16 + lg * 4 + r;
                int col = n0 + wn * 32 + nb * 16 + lr;
                if (OUT_BF16)
                    Cb[(size_t)row * N + col] = f2bf(acc[mb][nb][r]);
                else
                    Cf[(size_t)row * N + col] = acc[mb][nb][r];
            }
}

// ---------------------------------------------------------------------------
// RoPE in-place on bf16 qkv (q,k halves). 8 dims (4 pairs) per thread.
// ---------------------------------------------------------------------------
__global__ __launch_bounds__(256)
void rope_qk(unsigned short* __restrict__ qkvb, const float* __restrict__ fc) {
    int gid = blockIdx.x * 256 + threadIdx.x;
    int ch  = gid & 15;
    int h   = (gid >> 4) & 15;
    int sel = (gid >> 8) & 1;
    int row = gid >> 9;
    int t   = row & (T_ - 1);

    unsigned short* p = qkvb + (size_t)row * QKV_LD + sel * D_ + h * HD_ + ch * 8;
    uint4 v = *(uint4*)p;
    unsigned short* s = (unsigned short*)&v;
    const float* f = fc + ((size_t)t * 64 + ch * 4) * 2;
    float4 fA = *(const float4*)f;
    float4 fB = *(const float4*)(f + 4);
    float x0 = bf2f(s[0]), x1 = bf2f(s[1]), x2 = bf2f(s[2]), x3 = bf2f(s[3]);
    float x4 = bf2f(s[4]), x5 = bf2f(s[5]), x6 = bf2f(s[6]), x7 = bf2f(s[7]);
    unsigned short o[8];
    o[0] = f2bf(x0 * fA.x - x1 * fA.y);
    o[1] = f2bf(x1 * fA.x + x0 * fA.y);
    o[2] = f2bf(x2 * fA.z - x3 * fA.w);
    o[3] = f2bf(x3 * fA.z + x2 * fA.w);
    o[4] = f2bf(x4 * fB.x - x5 * fB.y);
    o[5] = f2bf(x5 * fB.x + x4 * fB.y);
    o[6] = f2bf(x6 * fB.z - x7 * fB.w);
    o[7] = f2bf(x7 * fB.z + x6 * fB.w);
    *(uint4*)p = *(uint4*)o;
}

// ---------------------------------------------------------------------------
// Build vT[b][h][d][t] bf16 from qkv v-part. 64-t tile per block.
// ---------------------------------------------------------------------------
__global__ __launch_bounds__(256)
void vT_build(const unsigned short* __restrict__ qkvb,
              unsigned short* __restrict__ vT) {
    __shared__ unsigned short tile[128][72];
    int t0 = blockIdx.x * 64;
    int bh = blockIdx.y;
    int b = bh >> 4, h = bh & 15;
    int tid = threadIdx.x;
    #pragma unroll
    for (int i = 0; i < 4; ++i) {
        int f = tid + 256 * i;
        int tr = f >> 4, ch = f & 15;
        uint4 v = *(const uint4*)(qkvb +
            (size_t)(b * T_ + t0 + tr) * QKV_LD + 2 * D_ + h * HD_ + ch * 8);
        unsigned short* s = (unsigned short*)&v;
        #pragma unroll
        for (int j = 0; j < 8; ++j) tile[ch * 8 + j][tr] = s[j];
    }
    __syncthreads();
    #pragma unroll
    for (int i = 0; i < 4; ++i) {
        int f = tid + 256 * i;
        int d = f >> 3, ch = f & 7;
        uint4 v = *(uint4*)(&tile[d][ch * 8]);
        *(uint4*)(vT + ((size_t)(bh * 128 + d)) * T_ + t0 + ch * 8) = v;
    }
}

// ---------------------------------------------------------------------------
// MFMA flash attention (causal), double-buffered K/V via global_load_lds.
// QBLK=64, KVBLK=64, 4 waves x 16 q-rows. Swapped QK^T (lane owns a q-row).
// ---------------------------------------------------------------------------
__global__ __launch_bounds__(256)
void attn_mfma(const unsigned short* __restrict__ qkvb,
               const unsigned short* __restrict__ vT,
               unsigned short* __restrict__ attnb) {
    __shared__ unsigned short Qs[64 * 128];      // reused as Ps after hoist
    __shared__ unsigned short Ks[2][64 * 128];
    __shared__ unsigned short Vts[2][128 * 64];

    int t = threadIdx.x;
    int wid = t >> 6, lane = t & 63;
    int lr = lane & 15, lg = lane >> 4;

    int wg  = blockIdx.x;
    int wgs = (wg & 7) * 128 + (wg >> 3);
    int bh  = wgs >> 5;
    int qt  = 31 - (wgs & 31);
    int b = bh >> 4, h = bh & 15;
    int qt0 = qt * 64;

    const unsigned short* qbase = qkvb + (size_t)(b * T_) * QKV_LD + h * HD_;
    const unsigned short* kbase = qbase + D_;
    const unsigned short* vbase = vT + (size_t)bh * 128 * T_;

    #pragma unroll
    for (int i = 0; i < 4; ++i) {
        int c = (wid * 4 + i) * 64 + lane;
        int row = c >> 4, ch = (c & 15) ^ (row & 7);
        gload_lds16(qbase + (size_t)(qt0 + row) * QKV_LD + ch * 8,
                    (char*)Qs + (wid * 4 + i) * 1024);
    }
    #pragma unroll
    for (int i = 0; i < 4; ++i) {
        int c = (wid * 4 + i) * 64 + lane;
        int rowk = c >> 4, chk = (c & 15) ^ (rowk & 7);
        gload_lds16(kbase + (size_t)rowk * QKV_LD + chk * 8,
                    (char*)Ks[0] + (wid * 4 + i) * 1024);
        int rowv = c >> 3, chv = (c & 7) ^ (rowv & 7);
        gload_lds16(vbase + (size_t)rowv * T_ + chv * 8,
                    (char*)Vts[0] + (wid * 4 + i) * 1024);
    }
    __syncthreads();

    bf16x8 qf[4];
    {
        int qrow = wid * 16 + lr;
        #pragma unroll
        for (int kd = 0; kd < 4; ++kd)
            qf[kd] = *(const bf16x8*)((const char*)Qs + qrow * 256 +
                       (((kd * 32 + lg * 8) * 2) ^ ((qrow & 7) << 4)));
    }
    __syncthreads();
    unsigned short* Ps = Qs;

    f32x4 o[8];
    #pragma unroll
    for (int nb = 0; nb < 8; ++nb) o[nb] = (f32x4){0.f, 0.f, 0.f, 0.f};
    float m_r = -1e30f, l_r = 0.f;
    const int qrow_g = qt0 + wid * 16 + lr;

    for (int kt = 0; kt <= qt; ++kt) {
        int cur = kt & 1;
        if (kt < qt) {
            #pragma unroll
            for (int i = 0; i < 4; ++i) {
                int c = (wid * 4 + i) * 64 + lane;
                int rowk = c >> 4, chk = (c & 15) ^ (rowk & 7);
                gload_lds16(kbase + (size_t)((kt + 1) * 64 + rowk) * QKV_LD + chk * 8,
                            (char*)Ks[cur ^ 1] + (wid * 4 + i) * 1024);
                int rowv = c >> 3, chv = (c & 7) ^ (rowv & 7);
                gload_lds16(vbase + (size_t)rowv * T_ + (kt + 1) * 64 + chv * 8,
                            (char*)Vts[cur ^ 1] + (wid * 4 + i) * 1024);
            }
        }
        const unsigned short* Kc = Ks[cur];
        const unsigned short* Vc = Vts[cur];

        f32x4 s[4];
        #pragma unroll
        for (int kb = 0; kb < 4; ++kb) s[kb] = (f32x4){0.f, 0.f, 0.f, 0.f};
        __builtin_amdgcn_s_setprio(1);
        #pragma unroll
        for (int kd = 0; kd < 4; ++kd) {
            #pragma unroll
            for (int kb = 0; kb < 4; ++kb) {
                int krow = kb * 16 + lr;
                bf16x8 kf = *(const bf16x8*)((const char*)Kc + krow * 256 +
                             (((kd * 32 + lg * 8) * 2) ^ ((krow & 7) << 4)));
                s[kb] = __builtin_amdgcn_mfma_f32_16x16x32_bf16(kf, qf[kd], s[kb], 0, 0, 0);
            }
        }
        __builtin_amdgcn_s_setprio(0);

        float sv[4][4];
        bool diag = (kt == qt);
        #pragma unroll
        for (int kb = 0; kb < 4; ++kb)
            #pragma unroll
            for (int r = 0; r < 4; ++r) {
                float v = s[kb][r] * SCALE;
                int key_g = kt * 64 + kb * 16 + 4 * lg + r;
                if (diag && key_g > qrow_g) v = -1e30f;
                sv[kb][r] = v;
            }
        float mt = -1e30f;
        #pragma unroll
        for (int kb = 0; kb < 4; ++kb)
            #pragma unroll
            for (int r = 0; r < 4; ++r) mt = fmaxf(mt, sv[kb][r]);
        mt = fmaxf(mt, __shfl_xor(mt, 16));
        mt = fmaxf(mt, __shfl_xor(mt, 32));

        bool defer = __all(mt - m_r <= 8.0f) != 0;
        float mnew  = defer ? m_r : fmaxf(m_r, mt);
        float alpha = defer ? 1.0f : __expf(m_r - mnew);

        float psum = 0.f;
        unsigned pw[4][2];
        #pragma unroll
        for (int kb = 0; kb < 4; ++kb) {
            float p0 = __expf(sv[kb][0] - mnew);
            float p1 = __expf(sv[kb][1] - mnew);
            float p2 = __expf(sv[kb][2] - mnew);
            float p3 = __expf(sv[kb][3] - mnew);
            psum += p0 + p1 + p2 + p3;
            pw[kb][0] = (unsigned)f2bf(p0) | ((unsigned)f2bf(p1) << 16);
            pw[kb][1] = (unsigned)f2bf(p2) | ((unsigned)f2bf(p3) << 16);
        }
        psum += __shfl_xor(psum, 16);
        psum += __shfl_xor(psum, 32);
        l_r = l_r * alpha + psum;
        m_r = mnew;

        if (!defer) {
            float a0 = __shfl(alpha, 4 * lg + 0, 16);
            float a1 = __shfl(alpha, 4 * lg + 1, 16);
            float a2 = __shfl(alpha, 4 * lg + 2, 16);
            float a3 = __shfl(alpha, 4 * lg + 3, 16);
            #pragma unroll
            for (int nb = 0; nb < 8; ++nb) {
                o[nb][0] *= a0; o[nb][1] *= a1; o[nb][2] *= a2; o[nb][3] *= a3;
            }
        }

        unsigned short* pbase = Ps + wid * 1152 + lr * 72;
        #pragma unroll
        for (int kb = 0; kb < 4; ++kb) {
            uint2 w; w.x = pw[kb][0]; w.y = pw[kb][1];
            *(uint2*)(pbase + kb * 16 + 4 * lg) = w;
        }
        __builtin_amdgcn_s_setprio(1);
        #pragma unroll
        for (int ks = 0; ks < 2; ++ks) {
            bf16x8 pa = *(const bf16x8*)(pbase + ks * 32 + 8 * lg);
            #pragma unroll
            for (int nb = 0; nb < 8; ++nb) {
                int vrow = nb * 16 + lr;
                bf16x8 vf = *(const bf16x8*)((const char*)Vc + vrow * 128 +
                             (((ks * 32 + lg * 8) * 2) ^ ((vrow & 7) << 4)));
                o[nb] = __builtin_amdgcn_mfma_f32_16x16x32_bf16(pa, vf, o[nb], 0, 0, 0);
            }
        }
        __builtin_amdgcn_s_setprio(0);
        __syncthreads();
    }

    float linv = 1.0f / l_r;
    float li0 = __shfl(linv, 4 * lg + 0, 16);
    float li1 = __shfl(linv, 4 * lg + 1, 16);
    float li2 = __shfl(linv, 4 * lg + 2, 16);
    float li3 = __shfl(linv, 4 * lg + 3, 16);
    #pragma unroll
    for (int nb = 0; nb < 8; ++nb) {
        float li[4] = {li0, li1, li2, li3};
        #pragma unroll
        for (int r = 0; r < 4; ++r) {
            int trow = qt0 + wid * 16 + 4 * lg + r;
            attnb[((size_t)(b * T_ + trow)) * D_ + h * HD_ + nb * 16 + lr] =
                f2bf(o[nb][r] * li[r]);
        }
    }
}

// ---------------------------------------------------------------------------
// Launch
// ---------------------------------------------------------------------------
extern "C" void kernel_launch(void* const* d_in, const int* in_sizes, int n_in,
                              void* d_out, int out_size, void* d_ws, size_t ws_size,
                              hipStream_t stream) {
    const float* x    = (const float*)d_in[0];
    const float* Wqkv = (const float*)d_in[1];
    const float* Wout = (const float*)d_in[2];
    const float* fc   = (const float*)d_in[3];
    float* out = (float*)d_out;

    char* ws = (char*)d_ws;
    unsigned short* xb    = (unsigned short*)(ws);                  // 16 MB (aliased w/ attnb)
    unsigned short* attnb = xb;
    unsigned short* WqkvT = (unsigned short*)(ws + 16777216);       // 24 MB
    unsigned short* WoutT = (unsigned short*)(ws + 41943040);       // 8 MB
    unsigned short* qkvb  = (unsigned short*)(ws + 50331648);       // 48 MB
    unsigned short* vT    = (unsigned short*)(ws + 100663296);      // 16 MB -> ends 112 MB

    dim3 blk(256);

    castx<<<4096, blk, 0, stream>>>(x, xb);
    wtrans<<<dim3(96, 32), blk, 0, stream>>>(Wqkv, WqkvT, 2048, 6144);
    wtrans<<<dim3(32, 32), blk, 0, stream>>>(Wout, WoutT, 2048, 2048);

    // qkv (bf16) = x @ Wqkv : M=4096 N=6144 K=2048 -> 16 x 48 = 768 wg
    gemm_p2<true><<<768, 512, 0, stream>>>(xb, WqkvT, nullptr, qkvb,
                                           4096, 6144, 2048);
    rope_qk<<<8192, blk, 0, stream>>>(qkvb, fc);
    vT_build<<<dim3(32, 32), blk, 0, stream>>>(qkvb, vT);
    attn_mfma<<<1024, blk, 0, stream>>>(qkvb, vT, attnb);
    // out (fp32) = attn @ Wout : M=4096 N=2048 K=2048 -> 16 x 16 = 256 wg
    gemm_p2<false><<<256, 512, 0, stream>>>(attnb, WoutT, out, nullptr,
                                            4096, 2048, 2048);
}

// Round 11
// 416.008 us; speedup vs baseline: 9.1320x; 1.0180x over previous
//
#include <hip/hip_runtime.h>
#include <math.h>

// Problem constants
#define B_   2
#define T_   2048
#define D_   2048
#define H_   16
#define HD_  128
#define QKV_LD 6144
#define SCALE 0.08838834764831845f  // 1/sqrt(128)

typedef __attribute__((ext_vector_type(4))) float f32x4;
typedef __attribute__((ext_vector_type(8))) short bf16x8;

static __device__ __forceinline__ unsigned short f2bf(float f) {
    unsigned u = __builtin_bit_cast(unsigned, f);
    return (unsigned short)((u + 0x7FFFu + ((u >> 16) & 1u)) >> 16);
}
static __device__ __forceinline__ float bf2f(unsigned short h) {
    unsigned u = ((unsigned)h) << 16;
    return __builtin_bit_cast(float, u);
}

// async global->LDS DMA, 16B per lane. LDS dest is wave-uniform base
// (HW writes base + lane*16); global src is per-lane.
static __device__ __forceinline__ void gload_lds16(const void* g, void* l) {
    __builtin_amdgcn_global_load_lds(
        (const __attribute__((address_space(1))) unsigned int*)g,
        (__attribute__((address_space(3))) unsigned int*)l, 16, 0, 0);
}

// ---------------------------------------------------------------------------
// cast x (fp32) -> bf16, 8 elems/thread
// ---------------------------------------------------------------------------
__global__ __launch_bounds__(256)
void castx(const float* __restrict__ in, unsigned short* __restrict__ out) {
    size_t i = (size_t)blockIdx.x * 256 + threadIdx.x;
    const float4* p = (const float4*)in + 2 * i;
    float4 a = p[0], b = p[1];
    unsigned short tmp[8] = {f2bf(a.x), f2bf(a.y), f2bf(a.z), f2bf(a.w),
                             f2bf(b.x), f2bf(b.y), f2bf(b.z), f2bf(b.w)};
    ((uint4*)out)[i] = *(uint4*)tmp;
}

// ---------------------------------------------------------------------------
// W[K][N] fp32 -> Wt[N][K] bf16 (transpose+cast), 64x64 tiles
// ---------------------------------------------------------------------------
__global__ __launch_bounds__(256)
void wtrans(const float* __restrict__ W, unsigned short* __restrict__ Wt,
            int K, int N) {
    __shared__ float tile[64][65];
    int k0 = blockIdx.y * 64, n0 = blockIdx.x * 64;
    int t = threadIdx.x;
    #pragma unroll
    for (int i = 0; i < 4; ++i) {
        int f = t + 256 * i;
        int r = f >> 4, c4 = f & 15;
        float4 v = *(const float4*)(W + (size_t)(k0 + r) * N + n0 + c4 * 4);
        tile[r][c4 * 4 + 0] = v.x; tile[r][c4 * 4 + 1] = v.y;
        tile[r][c4 * 4 + 2] = v.z; tile[r][c4 * 4 + 3] = v.w;
    }
    __syncthreads();
    #pragma unroll
    for (int i = 0; i < 2; ++i) {
        int f = t + 256 * i;
        int r = f >> 3, c = f & 7;
        unsigned short tmp[8];
        #pragma unroll
        for (int j = 0; j < 8; ++j) tmp[j] = f2bf(tile[c * 8 + j][r]);
        *(uint4*)(Wt + (size_t)(n0 + r) * K + k0 + c * 8) = *(uint4*)tmp;
    }
}

// ---------------------------------------------------------------------------
// 8-phase 256x256 bf16 MFMA GEMM (m201 template, plain HIP).
// C[M][N] = A[M][K] @ Bt[N][K]^T. BK=64, 2 K-tiles/iteration, 8 phases.
// 512 thr = 8 waves (2M x 4N); per-wave out 128x64 (8mb x 4nb frags).
// LDS 128 KB: region(slot,ab,half) = 16 KB (128 rows x 64 bf16, XOR-swz).
// Stage schedule (derived, region-safe): ph1 A0(b), ph2 A1(b), ph3 B0(a+2),
// ph4 B1(a+2), ph5 A0(a+2), ph6 A1(a+2), ph7 B0(b+2), ph8 B1(b+2).
// vmcnt(4) at ph4/ph8 only (retires exactly next tile's 8 issues; 2 halves
// stay in flight, never 0 mid-loop). Prologue 6 halves + vmcnt(4).
// ---------------------------------------------------------------------------
#define PHASE_MFMA(MG, NG, BF)                                                 \
    __builtin_amdgcn_s_barrier();                                              \
    asm volatile("s_waitcnt lgkmcnt(0)" ::: "memory");                         \
    __builtin_amdgcn_sched_barrier(0);                                         \
    __builtin_amdgcn_s_setprio(1);                                             \
    _Pragma("unroll")                                                          \
    for (int mb4 = 0; mb4 < 4; ++mb4)                                          \
        _Pragma("unroll")                                                      \
        for (int nb2 = 0; nb2 < 2; ++nb2)                                      \
            _Pragma("unroll")                                                  \
            for (int ks = 0; ks < 2; ++ks)                                     \
                acc[(MG)*4 + mb4][(NG)*2 + nb2] =                              \
                    __builtin_amdgcn_mfma_f32_16x16x32_bf16(                   \
                        af[mb4*2 + ks], BF[nb2*2 + ks],                        \
                        acc[(MG)*4 + mb4][(NG)*2 + nb2], 0, 0, 0);             \
    __builtin_amdgcn_s_setprio(0);

template <bool OUT_BF16>
__global__ __launch_bounds__(512, 2)
void gemm_8p(const unsigned short* __restrict__ A,
             const unsigned short* __restrict__ Bt,
             float* __restrict__ Cf, unsigned short* __restrict__ Cb,
             int M, int N, int K) {
    __shared__ unsigned short LDS[8 * 8192];   // 128 KB

    const int t = threadIdx.x;
    const int wid = t >> 6, lane = t & 63;
    const int wm = wid >> 2, wn = wid & 3;     // 2 x 4 wave grid
    const int lr = lane & 15, lg = lane >> 4;

    // XCD-aware swizzle (nwg % 8 == 0)
    const int gx  = N >> 8;
    const int nwg = gridDim.x;
    const int wg  = blockIdx.x;
    const int wgs = (wg & 7) * (nwg >> 3) + (wg >> 3);
    const int m0  = (wgs / gx) << 8;
    const int n0  = (wgs % gx) << 8;

    const unsigned short* Ab = A + (size_t)m0 * K;
    const unsigned short* Bb = Bt + (size_t)n0 * K;
    const int sr = lane >> 3, sc = lane & 7;

    // stage one 128x64 half-tile: 2 gload_lds16 per thread (16 KB total)
    auto stage = [&](int s, int ab, int h, int kt) {
        const unsigned short* base = ab ? Bb : Ab;
        char* dst = (char*)LDS + (((s * 2 + ab) * 2 + h) << 14);
        #pragma unroll
        for (int j = 0; j < 2; ++j) {
            int blk = wid * 2 + j;              // 0..15 KB-blocks
            int r   = blk * 8 + sr;             // 0..127
            int ch  = sc ^ (r & 7);             // inverse swizzle on source
            gload_lds16(base + (size_t)(h * 128 + r) * K + kt * 64 + ch * 8,
                        dst + blk * 1024);
        }
    };
    auto ldsA = [&](int s, int mb, int ks) -> bf16x8 {
        const char* rg = (const char*)LDS + (((s * 2 + 0) * 2 + wm) << 14);
        int lrow = mb * 16 + lr;
        return *(const bf16x8*)(rg + lrow * 128 +
                (((ks * 32 + lg * 8) * 2) ^ ((lrow & 7) << 4)));
    };
    auto ldsB = [&](int s, int nb, int ks) -> bf16x8 {
        const char* rg = (const char*)LDS + (((s * 2 + 1) * 2 + (wn >> 1)) << 14);
        int lrow = (wn & 1) * 64 + nb * 16 + lr;
        return *(const bf16x8*)(rg + lrow * 128 +
                (((ks * 32 + lg * 8) * 2) ^ ((lrow & 7) << 4)));
    };

    f32x4 acc[8][4];
    #pragma unroll
    for (int i = 0; i < 8; ++i)
        #pragma unroll
        for (int jn = 0; jn < 4; ++jn)
            acc[i][jn] = (f32x4){0.f, 0.f, 0.f, 0.f};

    bf16x8 af[8], b0f[4], b1f[4];
    auto loadAsub = [&](int s, int mg) {
        #pragma unroll
        for (int i = 0; i < 4; ++i) {
            af[i*2 + 0] = ldsA(s, mg*4 + i, 0);
            af[i*2 + 1] = ldsA(s, mg*4 + i, 1);
        }
    };
    auto loadBsub = [&](int s, int ng, bf16x8* bf) {
        #pragma unroll
        for (int i = 0; i < 2; ++i) {
            bf[i*2 + 0] = ldsB(s, ng*2 + i, 0);
            bf[i*2 + 1] = ldsB(s, ng*2 + i, 1);
        }
    };

    const int nt    = K >> 6;    // K-tiles (32)
    const int nIter = nt >> 1;   // 16

    // prologue: tile0 all 4 halves + B halves of tile1; keep 4 in flight
    stage(0,0,0,0); stage(0,0,1,0); stage(0,1,0,0); stage(0,1,1,0);
    stage(1,1,0,1); stage(1,1,1,1);
    asm volatile("s_waitcnt vmcnt(4)" ::: "memory");
    __builtin_amdgcn_s_barrier();

    for (int j = 0; j < nIter; ++j) {
        const int a = 2*j, b = 2*j + 1;
        const bool more = (j + 1 < nIter);

        // ======== tile a (slot 0) ========
        // ph1
        loadAsub(0, 0); loadBsub(0, 0, b0f);
        stage(1, 0, 0, b);                       // A0(b) -> slot1
        PHASE_MFMA(0, 0, b0f)
        __builtin_amdgcn_s_barrier();
        // ph2
        loadBsub(0, 1, b1f);
        stage(1, 0, 1, b);                       // A1(b) -> slot1
        PHASE_MFMA(0, 1, b1f)
        __builtin_amdgcn_s_barrier();
        // ph3
        loadAsub(0, 1);
        if (more) stage(0, 1, 0, a + 2);         // B0(a+2) -> slot0
        PHASE_MFMA(1, 0, b0f)
        __builtin_amdgcn_s_barrier();
        // ph4
        if (more) stage(0, 1, 1, a + 2);         // B1(a+2) -> slot0
        PHASE_MFMA(1, 1, b1f)
        if (more) { asm volatile("s_waitcnt vmcnt(4)" ::: "memory"); }
        else      { asm volatile("s_waitcnt vmcnt(0)" ::: "memory"); }
        __builtin_amdgcn_s_barrier();

        // ======== tile b (slot 1) ========
        // ph5
        loadAsub(1, 0); loadBsub(1, 0, b0f);
        if (more) stage(0, 0, 0, a + 2);         // A0(a+2) -> slot0
        PHASE_MFMA(0, 0, b0f)
        __builtin_amdgcn_s_barrier();
        // ph6
        loadBsub(1, 1, b1f);
        if (more) stage(0, 0, 1, a + 2);         // A1(a+2) -> slot0
        PHASE_MFMA(0, 1, b1f)
        __builtin_amdgcn_s_barrier();
        // ph7
        loadAsub(1, 1);
        if (more) stage(1, 1, 0, b + 2);         // B0(b+2) -> slot1
        PHASE_MFMA(1, 0, b0f)
        __builtin_amdgcn_s_barrier();
        // ph8
        if (more) stage(1, 1, 1, b + 2);         // B1(b+2) -> slot1
        PHASE_MFMA(1, 1, b1f)
        if (more) { asm volatile("s_waitcnt vmcnt(4)" ::: "memory"); }
        __builtin_amdgcn_s_barrier();
    }

    // epilogue: D layout col=lane&15, row=4*(lane>>4)+reg
    #pragma unroll
    for (int mb = 0; mb < 8; ++mb)
        #pragma unroll
        for (int nb = 0; nb < 4; ++nb)
            #pragma unroll
            for (int r = 0; r < 4; ++r) {
                int row = m0 + wm * 128 + mb * 16 + lg * 4 + r;
                int col = n0 + wn * 64 + nb * 16 + lr;
                if (OUT_BF16)
                    Cb[(size_t)row * N + col] = f2bf(acc[mb][nb][r]);
                else
                    Cf[(size_t)row * N + col] = acc[mb][nb][r];
            }
}

// ---------------------------------------------------------------------------
// bf16 MFMA GEMM (m97 structure, measured 859 TF R6) — used for out-proj.
// 128x128 tile, BK=64, 4 waves, global_load_lds w=16, pre-swizzled source.
// ---------------------------------------------------------------------------
template <bool OUT_BF16>
__global__ __launch_bounds__(256)
void gemm_bf16(const unsigned short* __restrict__ A,
               const unsigned short* __restrict__ Bt,
               float* __restrict__ Cf, unsigned short* __restrict__ Cb,
               int M, int N, int K) {
    __shared__ unsigned short As[128 * 64];
    __shared__ unsigned short Bs[128 * 64];
    int t = threadIdx.x;
    int wid = t >> 6, lane = t & 63;
    int wm = wid >> 1, wn = wid & 1;
    int lr = lane & 15, lg = lane >> 4;

    int nwg = gridDim.x * gridDim.y;
    int wg  = blockIdx.y * gridDim.x + blockIdx.x;
    int wgs = (wg & 7) * (nwg >> 3) + (wg >> 3);
    int m0 = (wgs / gridDim.x) * 128;
    int n0 = (wgs % gridDim.x) * 128;

    f32x4 acc[4][4];
    #pragma unroll
    for (int a = 0; a < 4; ++a)
        #pragma unroll
        for (int b = 0; b < 4; ++b)
            acc[a][b] = (f32x4){0.f, 0.f, 0.f, 0.f};

    for (int k0 = 0; k0 < K; k0 += 64) {
        #pragma unroll
        for (int i = 0; i < 4; ++i) {
            int c = (wid * 4 + i) * 64 + lane;
            int row = c >> 3, ch = (c & 7) ^ (row & 7);
            gload_lds16(A + (size_t)(m0 + row) * K + k0 + ch * 8,
                        (char*)As + (wid * 4 + i) * 1024);
            gload_lds16(Bt + (size_t)(n0 + row) * K + k0 + ch * 8,
                        (char*)Bs + (wid * 4 + i) * 1024);
        }
        __syncthreads();
        #pragma unroll
        for (int ks = 0; ks < 2; ++ks) {
            bf16x8 af[4], bfm[4];
            #pragma unroll
            for (int mb = 0; mb < 4; ++mb) {
                int row = wm * 64 + mb * 16 + lr;
                af[mb] = *(const bf16x8*)((const char*)As + row * 128 +
                          (((ks * 32 + lg * 8) * 2) ^ ((row & 7) << 4)));
            }
            #pragma unroll
            for (int nb = 0; nb < 4; ++nb) {
                int row = wn * 64 + nb * 16 + lr;
                bfm[nb] = *(const bf16x8*)((const char*)Bs + row * 128 +
                           (((ks * 32 + lg * 8) * 2) ^ ((row & 7) << 4)));
            }
            #pragma unroll
            for (int mb = 0; mb < 4; ++mb)
                #pragma unroll
                for (int nb = 0; nb < 4; ++nb)
                    acc[mb][nb] = __builtin_amdgcn_mfma_f32_16x16x32_bf16(
                        af[mb], bfm[nb], acc[mb][nb], 0, 0, 0);
        }
        __syncthreads();
    }
    #pragma unroll
    for (int mb = 0; mb < 4; ++mb)
        #pragma unroll
        for (int nb = 0; nb < 4; ++nb)
            #pragma unroll
            for (int r = 0; r < 4; ++r) {
                int row = m0 + wm * 64 + mb * 16 + lg * 4 + r;
                int col = n0 + wn * 64 + nb * 16 + lr;
                if (OUT_BF16)
                    Cb[(size_t)row * N + col] = f2bf(acc[mb][nb][r]);
                else
                    Cf[(size_t)row * N + col] = acc[mb][nb][r];
            }
}

// ---------------------------------------------------------------------------
// RoPE in-place on bf16 qkv (q,k halves). 8 dims (4 pairs) per thread.
// ---------------------------------------------------------------------------
__global__ __launch_bounds__(256)
void rope_qk(unsigned short* __restrict__ qkvb, const float* __restrict__ fc) {
    int gid = blockIdx.x * 256 + threadIdx.x;
    int ch  = gid & 15;
    int h   = (gid >> 4) & 15;
    int sel = (gid >> 8) & 1;
    int row = gid >> 9;
    int t   = row & (T_ - 1);

    unsigned short* p = qkvb + (size_t)row * QKV_LD + sel * D_ + h * HD_ + ch * 8;
    uint4 v = *(uint4*)p;
    unsigned short* s = (unsigned short*)&v;
    const float* f = fc + ((size_t)t * 64 + ch * 4) * 2;
    float4 fA = *(const float4*)f;
    float4 fB = *(const float4*)(f + 4);
    float x0 = bf2f(s[0]), x1 = bf2f(s[1]), x2 = bf2f(s[2]), x3 = bf2f(s[3]);
    float x4 = bf2f(s[4]), x5 = bf2f(s[5]), x6 = bf2f(s[6]), x7 = bf2f(s[7]);
    unsigned short o[8];
    o[0] = f2bf(x0 * fA.x - x1 * fA.y);
    o[1] = f2bf(x1 * fA.x + x0 * fA.y);
    o[2] = f2bf(x2 * fA.z - x3 * fA.w);
    o[3] = f2bf(x3 * fA.z + x2 * fA.w);
    o[4] = f2bf(x4 * fB.x - x5 * fB.y);
    o[5] = f2bf(x5 * fB.x + x4 * fB.y);
    o[6] = f2bf(x6 * fB.z - x7 * fB.w);
    o[7] = f2bf(x7 * fB.z + x6 * fB.w);
    *(uint4*)p = *(uint4*)o;
}

// ---------------------------------------------------------------------------
// Build vT[b][h][d][t] bf16 from qkv v-part. 64-t tile per block.
// ---------------------------------------------------------------------------
__global__ __launch_bounds__(256)
void vT_build(const unsigned short* __restrict__ qkvb,
              unsigned short* __restrict__ vT) {
    __shared__ unsigned short tile[128][72];
    int t0 = blockIdx.x * 64;
    int bh = blockIdx.y;
    int b = bh >> 4, h = bh & 15;
    int tid = threadIdx.x;
    #pragma unroll
    for (int i = 0; i < 4; ++i) {
        int f = tid + 256 * i;
        int tr = f >> 4, ch = f & 15;
        uint4 v = *(const uint4*)(qkvb +
            (size_t)(b * T_ + t0 + tr) * QKV_LD + 2 * D_ + h * HD_ + ch * 8);
        unsigned short* s = (unsigned short*)&v;
        #pragma unroll
        for (int j = 0; j < 8; ++j) tile[ch * 8 + j][tr] = s[j];
    }
    __syncthreads();
    #pragma unroll
    for (int i = 0; i < 4; ++i) {
        int f = tid + 256 * i;
        int d = f >> 3, ch = f & 7;
        uint4 v = *(uint4*)(&tile[d][ch * 8]);
        *(uint4*)(vT + ((size_t)(bh * 128 + d)) * T_ + t0 + ch * 8) = v;
    }
}

// ---------------------------------------------------------------------------
// MFMA flash attention (causal), double-buffered K/V via global_load_lds.
// QBLK=64, KVBLK=64, 4 waves x 16 q-rows. Swapped QK^T (lane owns a q-row).
// ---------------------------------------------------------------------------
__global__ __launch_bounds__(256)
void attn_mfma(const unsigned short* __restrict__ qkvb,
               const unsigned short* __restrict__ vT,
               unsigned short* __restrict__ attnb) {
    __shared__ unsigned short Qs[64 * 128];      // reused as Ps after hoist
    __shared__ unsigned short Ks[2][64 * 128];
    __shared__ unsigned short Vts[2][128 * 64];

    int t = threadIdx.x;
    int wid = t >> 6, lane = t & 63;
    int lr = lane & 15, lg = lane >> 4;

    int wg  = blockIdx.x;
    int wgs = (wg & 7) * 128 + (wg >> 3);
    int bh  = wgs >> 5;
    int qt  = 31 - (wgs & 31);
    int b = bh >> 4, h = bh & 15;
    int qt0 = qt * 64;

    const unsigned short* qbase = qkvb + (size_t)(b * T_) * QKV_LD + h * HD_;
    const unsigned short* kbase = qbase + D_;
    const unsigned short* vbase = vT + (size_t)bh * 128 * T_;

    #pragma unroll
    for (int i = 0; i < 4; ++i) {
        int c = (wid * 4 + i) * 64 + lane;
        int row = c >> 4, ch = (c & 15) ^ (row & 7);
        gload_lds16(qbase + (size_t)(qt0 + row) * QKV_LD + ch * 8,
                    (char*)Qs + (wid * 4 + i) * 1024);
    }
    #pragma unroll
    for (int i = 0; i < 4; ++i) {
        int c = (wid * 4 + i) * 64 + lane;
        int rowk = c >> 4, chk = (c & 15) ^ (rowk & 7);
        gload_lds16(kbase + (size_t)rowk * QKV_LD + chk * 8,
                    (char*)Ks[0] + (wid * 4 + i) * 1024);
        int rowv = c >> 3, chv = (c & 7) ^ (rowv & 7);
        gload_lds16(vbase + (size_t)rowv * T_ + chv * 8,
                    (char*)Vts[0] + (wid * 4 + i) * 1024);
    }
    __syncthreads();

    bf16x8 qf[4];
    {
        int qrow = wid * 16 + lr;
        #pragma unroll
        for (int kd = 0; kd < 4; ++kd)
            qf[kd] = *(const bf16x8*)((const char*)Qs + qrow * 256 +
                       (((kd * 32 + lg * 8) * 2) ^ ((qrow & 7) << 4)));
    }
    __syncthreads();
    unsigned short* Ps = Qs;

    f32x4 o[8];
    #pragma unroll
    for (int nb = 0; nb < 8; ++nb) o[nb] = (f32x4){0.f, 0.f, 0.f, 0.f};
    float m_r = -1e30f, l_r = 0.f;
    const int qrow_g = qt0 + wid * 16 + lr;

    for (int kt = 0; kt <= qt; ++kt) {
        int cur = kt & 1;
        if (kt < qt) {
            #pragma unroll
            for (int i = 0; i < 4; ++i) {
                int c = (wid * 4 + i) * 64 + lane;
                int rowk = c >> 4, chk = (c & 15) ^ (rowk & 7);
                gload_lds16(kbase + (size_t)((kt + 1) * 64 + rowk) * QKV_LD + chk * 8,
                            (char*)Ks[cur ^ 1] + (wid * 4 + i) * 1024);
                int rowv = c >> 3, chv = (c & 7) ^ (rowv & 7);
                gload_lds16(vbase + (size_t)rowv * T_ + (kt + 1) * 64 + chv * 8,
                            (char*)Vts[cur ^ 1] + (wid * 4 + i) * 1024);
            }
        }
        const unsigned short* Kc = Ks[cur];
        const unsigned short* Vc = Vts[cur];

        f32x4 s[4];
        #pragma unroll
        for (int kb = 0; kb < 4; ++kb) s[kb] = (f32x4){0.f, 0.f, 0.f, 0.f};
        __builtin_amdgcn_s_setprio(1);
        #pragma unroll
        for (int kd = 0; kd < 4; ++kd) {
            #pragma unroll
            for (int kb = 0; kb < 4; ++kb) {
                int krow = kb * 16 + lr;
                bf16x8 kf = *(const bf16x8*)((const char*)Kc + krow * 256 +
                             (((kd * 32 + lg * 8) * 2) ^ ((krow & 7) << 4)));
                s[kb] = __builtin_amdgcn_mfma_f32_16x16x32_bf16(kf, qf[kd], s[kb], 0, 0, 0);
            }
        }
        __builtin_amdgcn_s_setprio(0);

        float sv[4][4];
        bool diag = (kt == qt);
        #pragma unroll
        for (int kb = 0; kb < 4; ++kb)
            #pragma unroll
            for (int r = 0; r < 4; ++r) {
                float v = s[kb][r] * SCALE;
                int key_g = kt * 64 + kb * 16 + 4 * lg + r;
                if (diag && key_g > qrow_g) v = -1e30f;
                sv[kb][r] = v;
            }
        float mt = -1e30f;
        #pragma unroll
        for (int kb = 0; kb < 4; ++kb)
            #pragma unroll
            for (int r = 0; r < 4; ++r) mt = fmaxf(mt, sv[kb][r]);
        mt = fmaxf(mt, __shfl_xor(mt, 16));
        mt = fmaxf(mt, __shfl_xor(mt, 32));

        bool defer = __all(mt - m_r <= 8.0f) != 0;
        float mnew  = defer ? m_r : fmaxf(m_r, mt);
        float alpha = defer ? 1.0f : __expf(m_r - mnew);

        float psum = 0.f;
        unsigned pw[4][2];
        #pragma unroll
        for (int kb = 0; kb < 4; ++kb) {
            float p0 = __expf(sv[kb][0] - mnew);
            float p1 = __expf(sv[kb][1] - mnew);
            float p2 = __expf(sv[kb][2] - mnew);
            float p3 = __expf(sv[kb][3] - mnew);
            psum += p0 + p1 + p2 + p3;
            pw[kb][0] = (unsigned)f2bf(p0) | ((unsigned)f2bf(p1) << 16);
            pw[kb][1] = (unsigned)f2bf(p2) | ((unsigned)f2bf(p3) << 16);
        }
        psum += __shfl_xor(psum, 16);
        psum += __shfl_xor(psum, 32);
        l_r = l_r * alpha + psum;
        m_r = mnew;

        if (!defer) {
            float a0 = __shfl(alpha, 4 * lg + 0, 16);
            float a1 = __shfl(alpha, 4 * lg + 1, 16);
            float a2 = __shfl(alpha, 4 * lg + 2, 16);
            float a3 = __shfl(alpha, 4 * lg + 3, 16);
            #pragma unroll
            for (int nb = 0; nb < 8; ++nb) {
                o[nb][0] *= a0; o[nb][1] *= a1; o[nb][2] *= a2; o[nb][3] *= a3;
            }
        }

        unsigned short* pbase = Ps + wid * 1152 + lr * 72;
        #pragma unroll
        for (int kb = 0; kb < 4; ++kb) {
            uint2 w; w.x = pw[kb][0]; w.y = pw[kb][1];
            *(uint2*)(pbase + kb * 16 + 4 * lg) = w;
        }
        __builtin_amdgcn_s_setprio(1);
        #pragma unroll
        for (int ks = 0; ks < 2; ++ks) {
            bf16x8 pa = *(const bf16x8*)(pbase + ks * 32 + 8 * lg);
            #pragma unroll
            for (int nb = 0; nb < 8; ++nb) {
                int vrow = nb * 16 + lr;
                bf16x8 vf = *(const bf16x8*)((const char*)Vc + vrow * 128 +
                             (((ks * 32 + lg * 8) * 2) ^ ((vrow & 7) << 4)));
                o[nb] = __builtin_amdgcn_mfma_f32_16x16x32_bf16(pa, vf, o[nb], 0, 0, 0);
            }
        }
        __builtin_amdgcn_s_setprio(0);
        __syncthreads();
    }

    float linv = 1.0f / l_r;
    float li0 = __shfl(linv, 4 * lg + 0, 16);
    float li1 = __shfl(linv, 4 * lg + 1, 16);
    float li2 = __shfl(linv, 4 * lg + 2, 16);
    float li3 = __shfl(linv, 4 * lg + 3, 16);
    #pragma unroll
    for (int nb = 0; nb < 8; ++nb) {
        float li[4] = {li0, li1, li2, li3};
        #pragma unroll
        for (int r = 0; r < 4; ++r) {
            int trow = qt0 + wid * 16 + 4 * lg + r;
            attnb[((size_t)(b * T_ + trow)) * D_ + h * HD_ + nb * 16 + lr] =
                f2bf(o[nb][r] * li[r]);
        }
    }
}

// ---------------------------------------------------------------------------
// Launch
// ---------------------------------------------------------------------------
extern "C" void kernel_launch(void* const* d_in, const int* in_sizes, int n_in,
                              void* d_out, int out_size, void* d_ws, size_t ws_size,
                              hipStream_t stream) {
    const float* x    = (const float*)d_in[0];
    const float* Wqkv = (const float*)d_in[1];
    const float* Wout = (const float*)d_in[2];
    const float* fc   = (const float*)d_in[3];
    float* out = (float*)d_out;

    char* ws = (char*)d_ws;
    unsigned short* xb    = (unsigned short*)(ws);                  // 16 MB (aliased w/ attnb)
    unsigned short* attnb = xb;
    unsigned short* WqkvT = (unsigned short*)(ws + 16777216);       // 24 MB
    unsigned short* WoutT = (unsigned short*)(ws + 41943040);       // 8 MB
    unsigned short* qkvb  = (unsigned short*)(ws + 50331648);       // 48 MB
    unsigned short* vT    = (unsigned short*)(ws + 100663296);      // 16 MB -> ends 112 MB

    dim3 blk(256);

    castx<<<4096, blk, 0, stream>>>(x, xb);
    wtrans<<<dim3(96, 32), blk, 0, stream>>>(Wqkv, WqkvT, 2048, 6144);
    wtrans<<<dim3(32, 32), blk, 0, stream>>>(Wout, WoutT, 2048, 2048);

    // qkv (bf16) = x @ Wqkv : M=4096 N=6144 K=2048 -> 16 x 24 = 384 wg
    gemm_8p<true><<<384, 512, 0, stream>>>(xb, WqkvT, nullptr, qkvb,
                                           4096, 6144, 2048);
    rope_qk<<<8192, blk, 0, stream>>>(qkvb, fc);
    vT_build<<<dim3(32, 32), blk, 0, stream>>>(qkvb, vT);
    attn_mfma<<<1024, blk, 0, stream>>>(qkvb, vT, attnb);
    // out (fp32) = attn @ Wout : 128^2 tiles -> dim3(16, 32) = 512 wg
    gemm_bf16<false><<<dim3(16, 32), blk, 0, stream>>>(attnb, WoutT, out, nullptr,
                                                       4096, 2048, 2048);
}